// Round 2
// baseline (526.073 us; speedup 1.0000x reference)
//
#include <hip/hip_runtime.h>

typedef unsigned short u16;
typedef unsigned int u32;
typedef __attribute__((ext_vector_type(8))) short short8;
typedef __attribute__((ext_vector_type(4))) float f32x4;
typedef __attribute__((ext_vector_type(4))) u16 u16x4;

#define LOG2E 1.4426950408889634f
// scale folded with log2(e): S_scaled = S * (1/8) * log2(e); softmax uses exp2 directly.
#define SCL2 (0.125f * LOG2E)

static __device__ __forceinline__ float bf2f(u16 u) {
    return __uint_as_float(((unsigned)u) << 16);
}
static __device__ __forceinline__ u16 f2bf(float f) {
    unsigned u = __float_as_uint(f);
    unsigned r = (u + 0x7FFF + ((u >> 16) & 1)) >> 16;
    return (u16)r;
}
static __device__ __forceinline__ u32 pack2(float lo, float hi) {
    return (u32)f2bf(lo) | ((u32)f2bf(hi) << 16);
}
static __device__ __forceinline__ f32x4 mfma16(short8 a, short8 b, f32x4 c) {
    return __builtin_amdgcn_mfma_f32_16x16x32_bf16(a, b, c, 0, 0, 0);
}

// ---------------- cast x (fp32 -> bf16), vectorized ----------------
__global__ void cast_x_kernel(const float* __restrict__ x, u16* __restrict__ xb, int n) {
    int i = (blockIdx.x * blockDim.x + threadIdx.x) * 4;
    int stride = gridDim.x * blockDim.x * 4;
    for (; i < n; i += stride) {
        f32x4 v = *(const f32x4*)&x[i];
        u16x4 o;
        o.x = f2bf(v.x); o.y = f2bf(v.y); o.z = f2bf(v.z); o.w = f2bf(v.w);
        *(u16x4*)&xb[i] = o;
    }
}

// ---------------- transpose + cast: src[R][C] fp32 -> dst[C][R] bf16 ----------------
__global__ void transpose_cast_kernel(const float* __restrict__ src, u16* __restrict__ dst,
                                      int R, int C) {
    __shared__ float tile[32][33];
    int c0 = blockIdx.x * 32, r0 = blockIdx.y * 32;
    int tx = threadIdx.x, ty = threadIdx.y;
    int r = r0 + ty, c = c0 + tx;
    if (r < R && c < C) tile[ty][tx] = src[r * C + c];
    __syncthreads();
    int orow = c0 + ty;
    int oc   = r0 + tx;
    if (orow < C && oc < R) dst[orow * R + oc] = f2bf(tile[tx][ty]);
}

// ---------------- LoRA-A: xa = (x @ A) * 2.0, bf16 out, all 3 adapters ----------------
__global__ __launch_bounds__(64) void lora_a_kernel(
    const float* __restrict__ x,
    const float* __restrict__ qA, const float* __restrict__ kA, const float* __restrict__ vA,
    u16* __restrict__ xaq, u16* __restrict__ xak, u16* __restrict__ xav) {
    const int r = blockIdx.x;
    const int lane = threadIdx.x;
    float aq[16] = {}, ak[16] = {}, av[16] = {};
    const float* xr = x + (size_t)r * 2048;
    for (int kk = lane; kk < 2048; kk += 64) {
        const float xv = xr[kk];
        const f32x4* q4 = (const f32x4*)(qA + kk * 16);
        const f32x4* k4 = (const f32x4*)(kA + kk * 16);
        const f32x4* v4 = (const f32x4*)(vA + kk * 16);
#pragma unroll
        for (int t = 0; t < 4; ++t) {
            f32x4 a = q4[t], b = k4[t], cc = v4[t];
#pragma unroll
            for (int e = 0; e < 4; ++e) {
                aq[t * 4 + e] += xv * a[e];
                ak[t * 4 + e] += xv * b[e];
                av[t * 4 + e] += xv * cc[e];
            }
        }
    }
#pragma unroll
    for (int j = 0; j < 16; ++j) {
#pragma unroll
        for (int off = 1; off < 64; off <<= 1) {
            aq[j] += __shfl_xor(aq[j], off);
            ak[j] += __shfl_xor(ak[j], off);
            av[j] += __shfl_xor(av[j], off);
        }
    }
    if (lane == 0) {
#pragma unroll
        for (int j = 0; j < 16; ++j) {
            xaq[r * 16 + j] = f2bf(aq[j] * 2.0f);
            xak[r * 16 + j] = f2bf(ak[j] * 2.0f);
            xav[r * 16 + j] = f2bf(av[j] * 2.0f);
        }
    }
}

// ---------------- GEMM: C[M][Nn] = A[M][2048] @ Bt[Nn][2048]^T (+ rank16 LoRA) ----------------
template <int LORA, int OUTF32>
__global__ __launch_bounds__(256) void gemm_kernel(
    const u16* __restrict__ A, const u16* __restrict__ Bt, void* __restrict__ Cout, int Nn,
    const u16* __restrict__ xa, const u16* __restrict__ LBt) {
    constexpr int K = 2048;
    constexpr int LS = 72;
    __shared__ u16 As[128 * LS];
    __shared__ u16 Bs[128 * LS];
    const int tid = threadIdx.x;
    const int wid = tid >> 6, lane = tid & 63;
    const int mbase = blockIdx.x * 128;
    const int nbase = blockIdx.y * 128;
    const int wrow = (wid >> 1) * 64, wcol = (wid & 1) * 64;
    const int fr = lane & 15, fk = (lane >> 4) * 8;
    const int srow = tid >> 3, soff = (tid & 7) * 8;
    f32x4 acc[4][4] = {};
    const u16* Ag = A + (size_t)mbase * K;
    const u16* Bg = Bt + (size_t)nbase * K;
    for (int kt = 0; kt < K; kt += 64) {
        short8 ar[4], br[4];
#pragma unroll
        for (int i = 0; i < 4; ++i) {
            ar[i] = *(const short8*)&Ag[(size_t)(srow + 32 * i) * K + kt + soff];
            br[i] = *(const short8*)&Bg[(size_t)(srow + 32 * i) * K + kt + soff];
        }
        __syncthreads();
#pragma unroll
        for (int i = 0; i < 4; ++i) {
            *(short8*)&As[(srow + 32 * i) * LS + soff] = ar[i];
            *(short8*)&Bs[(srow + 32 * i) * LS + soff] = br[i];
        }
        __syncthreads();
#pragma unroll
        for (int ks = 0; ks < 2; ++ks) {
            short8 af[4], bfr[4];
#pragma unroll
            for (int i = 0; i < 4; ++i) {
                af[i]  = *(const short8*)&As[(wrow + i * 16 + fr) * LS + ks * 32 + fk];
                bfr[i] = *(const short8*)&Bs[(wcol + i * 16 + fr) * LS + ks * 32 + fk];
            }
#pragma unroll
            for (int mi = 0; mi < 4; ++mi)
#pragma unroll
                for (int ni = 0; ni < 4; ++ni)
                    acc[mi][ni] = mfma16(af[mi], bfr[ni], acc[mi][ni]);
        }
    }
    if (LORA) {
        const int rr = tid >> 1, hh = (tid & 1) * 8;
        short8 xv = *(const short8*)&xa[(mbase + rr) * 16 + hh];
        short8 lv = *(const short8*)&LBt[(nbase + rr) * 16 + hh];
        short8 z = {};
        __syncthreads();
        *(short8*)&As[rr * LS + hh] = xv;
        *(short8*)&As[rr * LS + 16 + hh] = z;
        *(short8*)&Bs[rr * LS + hh] = lv;
        *(short8*)&Bs[rr * LS + 16 + hh] = z;
        __syncthreads();
        short8 af[4], bfr[4];
#pragma unroll
        for (int i = 0; i < 4; ++i) {
            af[i]  = *(const short8*)&As[(wrow + i * 16 + fr) * LS + fk];
            bfr[i] = *(const short8*)&Bs[(wcol + i * 16 + fr) * LS + fk];
        }
#pragma unroll
        for (int mi = 0; mi < 4; ++mi)
#pragma unroll
            for (int ni = 0; ni < 4; ++ni)
                acc[mi][ni] = mfma16(af[mi], bfr[ni], acc[mi][ni]);
    }
    const int rb = mbase + wrow + ((lane >> 4) << 2);
    const int cb = nbase + wcol + fr;
    if (OUTF32) {
        float* C = (float*)Cout;
#pragma unroll
        for (int mi = 0; mi < 4; ++mi)
#pragma unroll
            for (int j = 0; j < 4; ++j) {
                const size_t ro = (size_t)(rb + mi * 16 + j) * Nn;
#pragma unroll
                for (int ni = 0; ni < 4; ++ni) C[ro + cb + ni * 16] = acc[mi][ni][j];
            }
    } else {
        u16* C = (u16*)Cout;
#pragma unroll
        for (int mi = 0; mi < 4; ++mi)
#pragma unroll
            for (int j = 0; j < 4; ++j) {
                const size_t ro = (size_t)(rb + mi * 16 + j) * Nn;
#pragma unroll
                for (int ni = 0; ni < 4; ++ni) C[ro + cb + ni * 16] = f2bf(acc[mi][ni][j]);
            }
    }
}

// ---------------- RoPE in place on bf16 [4096][width] ----------------
__global__ void rope_kernel(u16* __restrict__ t, const float* __restrict__ cosb,
                            const float* __restrict__ sinb, int width, int shift) {
    int idx = blockIdx.x * blockDim.x + threadIdx.x;
    int base = idx * 8;
    int row = base >> shift;
    int within = base & (width - 1);
    int d0 = within & 63;
    int i0 = d0 >> 1;
    int s = row & 1023;
    short8 v = *(short8*)&t[base];
    f32x4 cv = *(const f32x4*)&cosb[s * 32 + i0];
    f32x4 sv = *(const f32x4*)&sinb[s * 32 + i0];
#pragma unroll
    for (int p = 0; p < 4; ++p) {
        float x0 = bf2f((u16)v[2 * p]);
        float x1 = bf2f((u16)v[2 * p + 1]);
        float r0 = x0 * cv[p] - x1 * sv[p];
        float r1 = x0 * sv[p] + x1 * cv[p];
        v[2 * p] = (short)f2bf(r0);
        v[2 * p + 1] = (short)f2bf(r1);
    }
    *(short8*)&t[base] = v;
}

// ---------------- causal GQA flash attention: zero LDS, zero barriers ----------------
// grid (qt=16, h=32, b=4), 256 thr = 4 independent waves; wave wid owns q rows qt*64+wid*16..+15.
// Swapped QK^T: S^T = mfma(K,Q) => lane (fr,hi) holds P[q=fr][kv_l=mi*16+hi*4+j] for its q.
// PV: O^T = mfma(V^T, P) with V^T fragments straight from global (VT2 buffer).
__global__ __launch_bounds__(256) void attn_kernel(
    const u16* __restrict__ q, const u16* __restrict__ k, const u16* __restrict__ vt,
    u16* __restrict__ ctx) {
    const int qt = blockIdx.x, h = blockIdx.y, b = blockIdx.z;
    const int g = h >> 2;
    const int tid = threadIdx.x, wid = tid >> 6, lane = tid & 63;
    const int fr = lane & 15, hi = lane >> 4, fk = hi * 8;
    const int qrow0 = qt * 64 + wid * 16;
    const int sq = qrow0 + fr;  // this lane's sequence position (q row AND output col)
    short8 qf[2];
    {
        const u16* qp = &q[((size_t)(b * 1024 + sq)) * 2048 + h * 64];
        qf[0] = *(const short8*)&qp[fk];
        qf[1] = *(const short8*)&qp[32 + fk];
    }
    f32x4 o[4] = {};
    float m = -3.0e38f, l = 0.0f;
    const u16* kbase = k + ((size_t)b * 1024) * 512 + g * 64;
    const u16* vbase = vt + ((size_t)(g * 64)) * 4096 + b * 1024;
    // shfl sources for P-fragment reshape (independent of ks)
    const int srcA = fr | ((2 * (hi & 1)) << 4);
    const int srcB = srcA + 16;
    for (int kt = 0; kt <= qt; ++kt) {
        const bool diag = (kt == qt);
        const int miq = diag ? wid : 3;
        const u16* kp = kbase + (size_t)(kt * 64) * 512;
        f32x4 s[4];
#pragma unroll
        for (int mi = 0; mi < 4; ++mi) {
            if (mi <= miq) {
                short8 kf0 = *(const short8*)&kp[(size_t)(mi * 16 + fr) * 512 + fk];
                short8 kf1 = *(const short8*)&kp[(size_t)(mi * 16 + fr) * 512 + 32 + fk];
                f32x4 z = {};
                z = mfma16(kf0, qf[0], z);
                z = mfma16(kf1, qf[1], z);
#pragma unroll
                for (int j = 0; j < 4; ++j) {
                    float val = z[j] * SCL2;
                    if (diag && (kt * 64 + mi * 16 + hi * 4 + j > sq)) val = -3.0e38f;
                    s[mi][j] = val;
                }
            } else {
                s[mi][0] = -3.0e38f; s[mi][1] = -3.0e38f;
                s[mi][2] = -3.0e38f; s[mi][3] = -3.0e38f;
            }
        }
        // max over this lane's 16 values (all same q), then across the 4 lanes of the q-group
        float pmax = fmaxf(fmaxf(fmaxf(s[0][0], s[0][1]), fmaxf(s[0][2], s[0][3])),
                           fmaxf(fmaxf(s[1][0], s[1][1]), fmaxf(s[1][2], s[1][3])));
        pmax = fmaxf(pmax, fmaxf(fmaxf(fmaxf(s[2][0], s[2][1]), fmaxf(s[2][2], s[2][3])),
                                 fmaxf(fmaxf(s[3][0], s[3][1]), fmaxf(s[3][2], s[3][3]))));
        pmax = fmaxf(pmax, __shfl_xor(pmax, 16));
        pmax = fmaxf(pmax, __shfl_xor(pmax, 32));
        const float mnew = fmaxf(m, pmax);
        const float fsc = exp2f(m - mnew);
        float rs = 0.0f;
        u32 pk[4][2];
#pragma unroll
        for (int mi = 0; mi < 4; ++mi) {
            float p0 = exp2f(s[mi][0] - mnew);
            float p1 = exp2f(s[mi][1] - mnew);
            float p2 = exp2f(s[mi][2] - mnew);
            float p3 = exp2f(s[mi][3] - mnew);
            rs += (p0 + p1) + (p2 + p3);
            pk[mi][0] = pack2(p0, p1);
            pk[mi][1] = pack2(p2, p3);
        }
        rs += __shfl_xor(rs, 16);
        rs += __shfl_xor(rs, 32);
        l = l * fsc + rs;
        m = mnew;
#pragma unroll
        for (int dn = 0; dn < 4; ++dn)
#pragma unroll
            for (int j = 0; j < 4; ++j) o[dn][j] *= fsc;
        // PV: for each ks (kv half), build P B-fragment via shfl, mfma with V^T A-fragments
        const int ksmax = diag ? (wid >> 1) : 1;
        const u16* vp = vbase + kt * 64;
#pragma unroll
        for (int ks = 0; ks < 2; ++ks) {
            if (ks > ksmax) continue;
            u32 a0 = __shfl(pk[2 * ks][0], srcA);
            u32 a1 = __shfl(pk[2 * ks][1], srcA);
            u32 b0 = __shfl(pk[2 * ks][0], srcB);
            u32 b1 = __shfl(pk[2 * ks][1], srcB);
            u32 c0 = __shfl(pk[2 * ks + 1][0], srcA);
            u32 c1 = __shfl(pk[2 * ks + 1][1], srcA);
            u32 d0 = __shfl(pk[2 * ks + 1][0], srcB);
            u32 d1 = __shfl(pk[2 * ks + 1][1], srcB);
            union { u32 w[4]; short8 s8; } pu;
            pu.w[0] = (hi < 2) ? a0 : c0;
            pu.w[1] = (hi < 2) ? a1 : c1;
            pu.w[2] = (hi < 2) ? b0 : d0;
            pu.w[3] = (hi < 2) ? b1 : d1;
            short8 pf = pu.s8;
#pragma unroll
            for (int dn = 0; dn < 4; ++dn) {
                short8 vf = *(const short8*)&vp[(size_t)(dn * 16 + fr) * 4096 + ks * 32 + fk];
                o[dn] = mfma16(vf, pf, o[dn]);
            }
        }
    }
    const float linv = 1.0f / l;
    const size_t obase = ((size_t)(b * 1024 + sq)) * 2048 + h * 64;
#pragma unroll
    for (int dn = 0; dn < 4; ++dn) {
        u16x4 w;
#pragma unroll
        for (int j = 0; j < 4; ++j) w[j] = f2bf(o[dn][j] * linv);
        *(u16x4*)&ctx[obase + dn * 16 + hi * 4] = w;
    }
}

extern "C" void kernel_launch(void* const* d_in, const int* in_sizes, int n_in,
                              void* d_out, int out_size, void* d_ws, size_t ws_size,
                              hipStream_t stream) {
    const float* x    = (const float*)d_in[0];
    const float* fcos = (const float*)d_in[1];
    const float* fsin = (const float*)d_in[2];
    const float* Wq   = (const float*)d_in[3];
    const float* Wk   = (const float*)d_in[4];
    const float* Wv   = (const float*)d_in[5];
    const float* Wo   = (const float*)d_in[6];
    const float* qA   = (const float*)d_in[7];
    const float* qB   = (const float*)d_in[8];
    const float* kA   = (const float*)d_in[9];
    const float* kB   = (const float*)d_in[10];
    const float* vA   = (const float*)d_in[11];
    const float* vB   = (const float*)d_in[12];
    float* out = (float*)d_out;

    char* ws = (char*)d_ws;
    size_t off = 0;
    auto alloc = [&](size_t bytes) { char* p = ws + off; off += (bytes + 255) & ~(size_t)255; return p; };
    u16* xb   = (u16*)alloc(4096 * 2048 * 2);
    u16* WqT  = (u16*)alloc(2048 * 2048 * 2);
    u16* WkT  = (u16*)alloc(512 * 2048 * 2);
    u16* WvT  = (u16*)alloc(512 * 2048 * 2);
    u16* WoT  = (u16*)alloc(2048 * 2048 * 2);
    u16* qBt  = (u16*)alloc(2048 * 16 * 2);
    u16* kBt  = (u16*)alloc(512 * 16 * 2);
    u16* vBt  = (u16*)alloc(512 * 16 * 2);
    u16* xaq  = (u16*)alloc(4096 * 16 * 2);
    u16* xak  = (u16*)alloc(4096 * 16 * 2);
    u16* xav  = (u16*)alloc(4096 * 16 * 2);
    u16* qbuf = (u16*)alloc(4096 * 2048 * 2);
    u16* kbuf = (u16*)alloc(4096 * 512 * 2);
    u16* VT2  = (u16*)alloc(512 * 4096 * 2);   // V^T: [(g*64+d)][b*1024+s]
    u16* ctx  = (u16*)alloc(4096 * 2048 * 2);

    cast_x_kernel<<<2048, 256, 0, stream>>>(x, xb, 4096 * 2048);

    dim3 tb(32, 32);
    transpose_cast_kernel<<<dim3(64, 64), tb, 0, stream>>>(Wq, WqT, 2048, 2048);
    transpose_cast_kernel<<<dim3(16, 64), tb, 0, stream>>>(Wk, WkT, 2048, 512);
    transpose_cast_kernel<<<dim3(16, 64), tb, 0, stream>>>(Wv, WvT, 2048, 512);
    transpose_cast_kernel<<<dim3(64, 64), tb, 0, stream>>>(Wo, WoT, 2048, 2048);
    transpose_cast_kernel<<<dim3(64, 1), tb, 0, stream>>>(qB, qBt, 16, 2048);
    transpose_cast_kernel<<<dim3(16, 1), tb, 0, stream>>>(kB, kBt, 16, 512);
    transpose_cast_kernel<<<dim3(16, 1), tb, 0, stream>>>(vB, vBt, 16, 512);

    lora_a_kernel<<<4096, 64, 0, stream>>>(x, qA, kA, vA, xaq, xak, xav);

    gemm_kernel<1, 0><<<dim3(32, 16), 256, 0, stream>>>(xb, WqT, qbuf, 2048, xaq, qBt);
    gemm_kernel<1, 0><<<dim3(32, 4), 256, 0, stream>>>(xb, WkT, kbuf, 512, xak, kBt);
    // V computed TRANSPOSED: VT2[feat][b*1024+s] = (x@Wv + LoRA)^T via operand swap
    gemm_kernel<1, 0><<<dim3(4, 32), 256, 0, stream>>>(WvT, xb, VT2, 4096, vBt, xav);

    rope_kernel<<<4096, 256, 0, stream>>>(qbuf, fcos, fsin, 2048, 11);
    rope_kernel<<<1024, 256, 0, stream>>>(kbuf, fcos, fsin, 512, 9);

    attn_kernel<<<dim3(16, 32, 4), 256, 0, stream>>>(qbuf, kbuf, VT2, ctx);

    gemm_kernel<0, 1><<<dim3(32, 16), 256, 0, stream>>>(ctx, WoT, out, 2048, nullptr, nullptr);
}

// Round 3
// 419.450 us; speedup vs baseline: 1.2542x; 1.2542x over previous
//
#include <hip/hip_runtime.h>

typedef unsigned short u16;
typedef unsigned int u32;
typedef __attribute__((ext_vector_type(8))) short short8;
typedef __attribute__((ext_vector_type(4))) float f32x4;
typedef __attribute__((ext_vector_type(4))) u16 u16x4;

#define LOG2E 1.4426950408889634f
#define SCL2 (0.125f * LOG2E)

static __device__ __forceinline__ float bf2f(u16 u) {
    return __uint_as_float(((unsigned)u) << 16);
}
static __device__ __forceinline__ u16 f2bf(float f) {
    unsigned u = __float_as_uint(f);
    unsigned r = (u + 0x7FFF + ((u >> 16) & 1)) >> 16;
    return (u16)r;
}
static __device__ __forceinline__ u32 pack2(float lo, float hi) {
    return (u32)f2bf(lo) | ((u32)f2bf(hi) << 16);
}
static __device__ __forceinline__ f32x4 mfma16(short8 a, short8 b, f32x4 c) {
    return __builtin_amdgcn_mfma_f32_16x16x32_bf16(a, b, c, 0, 0, 0);
}
static __device__ __forceinline__ void gload_lds16(const void* g, void* l) {
    __builtin_amdgcn_global_load_lds(
        (const __attribute__((address_space(1))) void*)g,
        (__attribute__((address_space(3))) void*)l, 16, 0, 0);
}

// ---------------- cast x (fp32 -> bf16), vectorized ----------------
__global__ void cast_x_kernel(const float* __restrict__ x, u16* __restrict__ xb, int n) {
    int i = (blockIdx.x * blockDim.x + threadIdx.x) * 4;
    int stride = gridDim.x * blockDim.x * 4;
    for (; i < n; i += stride) {
        f32x4 v = *(const f32x4*)&x[i];
        u16x4 o;
        o.x = f2bf(v.x); o.y = f2bf(v.y); o.z = f2bf(v.z); o.w = f2bf(v.w);
        *(u16x4*)&xb[i] = o;
    }
}

// ---------------- transpose + cast: src[R][C] fp32 -> dst[C][R] bf16 ----------------
__global__ void transpose_cast_kernel(const float* __restrict__ src, u16* __restrict__ dst,
                                      int R, int C) {
    __shared__ float tile[32][33];
    int c0 = blockIdx.x * 32, r0 = blockIdx.y * 32;
    int tx = threadIdx.x, ty = threadIdx.y;
    int r = r0 + ty, c = c0 + tx;
    if (r < R && c < C) tile[ty][tx] = src[r * C + c];
    __syncthreads();
    int orow = c0 + ty;
    int oc   = r0 + tx;
    if (orow < C && oc < R) dst[orow * R + oc] = f2bf(tile[tx][ty]);
}

// ---------------- LoRA-A: xa = (x @ A) * 2.0, bf16 out, all 3 adapters ----------------
__global__ __launch_bounds__(64) void lora_a_kernel(
    const float* __restrict__ x,
    const float* __restrict__ qA, const float* __restrict__ kA, const float* __restrict__ vA,
    u16* __restrict__ xaq, u16* __restrict__ xak, u16* __restrict__ xav) {
    const int r = blockIdx.x;
    const int lane = threadIdx.x;
    float aq[16] = {}, ak[16] = {}, av[16] = {};
    const float* xr = x + (size_t)r * 2048;
    for (int kk = lane; kk < 2048; kk += 64) {
        const float xv = xr[kk];
        const f32x4* q4 = (const f32x4*)(qA + kk * 16);
        const f32x4* k4 = (const f32x4*)(kA + kk * 16);
        const f32x4* v4 = (const f32x4*)(vA + kk * 16);
#pragma unroll
        for (int t = 0; t < 4; ++t) {
            f32x4 a = q4[t], b = k4[t], cc = v4[t];
#pragma unroll
            for (int e = 0; e < 4; ++e) {
                aq[t * 4 + e] += xv * a[e];
                ak[t * 4 + e] += xv * b[e];
                av[t * 4 + e] += xv * cc[e];
            }
        }
    }
#pragma unroll
    for (int j = 0; j < 16; ++j) {
#pragma unroll
        for (int off = 1; off < 64; off <<= 1) {
            aq[j] += __shfl_xor(aq[j], off);
            ak[j] += __shfl_xor(ak[j], off);
            av[j] += __shfl_xor(av[j], off);
        }
    }
    if (lane == 0) {
#pragma unroll
        for (int j = 0; j < 16; ++j) {
            xaq[r * 16 + j] = f2bf(aq[j] * 2.0f);
            xak[r * 16 + j] = f2bf(ak[j] * 2.0f);
            xav[r * 16 + j] = f2bf(av[j] * 2.0f);
        }
    }
}

// ---------------- GEMM (m97 recipe): C[M][Nn] = A[M][2048] @ Bt[Nn][2048]^T (+ rank16 LoRA) ----
// 128x128 tile, BK=64, 4 waves; staging via global_load_lds width=16 into LINEAR [128][64] LDS.
template <int LORA, int OUTF32>
__global__ __launch_bounds__(256) void gemm_kernel(
    const u16* __restrict__ A, const u16* __restrict__ Bt, void* __restrict__ Cout, int Nn,
    const u16* __restrict__ xa, const u16* __restrict__ LBt) {
    constexpr int K = 2048;
    __shared__ u16 As[128 * 64];
    __shared__ u16 Bs[128 * 64];
    const int tid = threadIdx.x;
    const int wid = tid >> 6, lane = tid & 63;
    const int mbase = blockIdx.x * 128;
    const int nbase = blockIdx.y * 128;
    const int wrow = (wid >> 1) * 64, wcol = (wid & 1) * 64;
    const int fr = lane & 15, fk = (lane >> 4) * 8;
    const int l8 = lane >> 3, c8 = (lane & 7) * 8;   // lane -> (row-in-8block, col)
    f32x4 acc[4][4] = {};
    const u16* Ag = A + (size_t)mbase * K;
    const u16* Bg = Bt + (size_t)nbase * K;
    for (int kt = 0; kt < K; kt += 64) {
        __syncthreads();   // all frag reads of previous tile done
#pragma unroll
        for (int i = 0; i < 4; ++i) {
            const int r8 = (i * 4 + wid) * 8;        // wave-uniform 8-row block
            gload_lds16(&Ag[(size_t)(r8 + l8) * K + kt + c8], &As[r8 * 64]);
            gload_lds16(&Bg[(size_t)(r8 + l8) * K + kt + c8], &Bs[r8 * 64]);
        }
        __syncthreads();   // vmcnt(0) drained here by compiler
#pragma unroll
        for (int ks = 0; ks < 2; ++ks) {
            short8 af[4], bfr[4];
#pragma unroll
            for (int i = 0; i < 4; ++i) {
                af[i]  = *(const short8*)&As[(wrow + i * 16 + fr) * 64 + ks * 32 + fk];
                bfr[i] = *(const short8*)&Bs[(wcol + i * 16 + fr) * 64 + ks * 32 + fk];
            }
#pragma unroll
            for (int mi = 0; mi < 4; ++mi)
#pragma unroll
                for (int ni = 0; ni < 4; ++ni)
                    acc[mi][ni] = mfma16(af[mi], bfr[ni], acc[mi][ni]);
        }
    }
    if (LORA) {
        const int rr = tid >> 1, hh = (tid & 1) * 8;
        short8 xv = *(const short8*)&xa[(mbase + rr) * 16 + hh];
        short8 lv = *(const short8*)&LBt[(nbase + rr) * 16 + hh];
        short8 z = {};
        __syncthreads();
        *(short8*)&As[rr * 64 + hh] = xv;
        *(short8*)&As[rr * 64 + 16 + hh] = z;
        *(short8*)&Bs[rr * 64 + hh] = lv;
        *(short8*)&Bs[rr * 64 + 16 + hh] = z;
        __syncthreads();
        short8 af[4], bfr[4];
#pragma unroll
        for (int i = 0; i < 4; ++i) {
            af[i]  = *(const short8*)&As[(wrow + i * 16 + fr) * 64 + fk];
            bfr[i] = *(const short8*)&Bs[(wcol + i * 16 + fr) * 64 + fk];
        }
#pragma unroll
        for (int mi = 0; mi < 4; ++mi)
#pragma unroll
            for (int ni = 0; ni < 4; ++ni)
                acc[mi][ni] = mfma16(af[mi], bfr[ni], acc[mi][ni]);
    }
    const int rb = mbase + wrow + ((lane >> 4) << 2);
    const int cb = nbase + wcol + fr;
    if (OUTF32) {
        float* C = (float*)Cout;
#pragma unroll
        for (int mi = 0; mi < 4; ++mi)
#pragma unroll
            for (int j = 0; j < 4; ++j) {
                const size_t ro = (size_t)(rb + mi * 16 + j) * Nn;
#pragma unroll
                for (int ni = 0; ni < 4; ++ni) C[ro + cb + ni * 16] = acc[mi][ni][j];
            }
    } else {
        u16* C = (u16*)Cout;
#pragma unroll
        for (int mi = 0; mi < 4; ++mi)
#pragma unroll
            for (int j = 0; j < 4; ++j) {
                const size_t ro = (size_t)(rb + mi * 16 + j) * Nn;
#pragma unroll
                for (int ni = 0; ni < 4; ++ni) C[ro + cb + ni * 16] = f2bf(acc[mi][ni][j]);
            }
    }
}

// ---------------- RoPE in place on bf16 [4096][width] ----------------
__global__ void rope_kernel(u16* __restrict__ t, const float* __restrict__ cosb,
                            const float* __restrict__ sinb, int width, int shift) {
    int idx = blockIdx.x * blockDim.x + threadIdx.x;
    int base = idx * 8;
    int row = base >> shift;
    int within = base & (width - 1);
    int d0 = within & 63;
    int i0 = d0 >> 1;
    int s = row & 1023;
    short8 v = *(short8*)&t[base];
    f32x4 cv = *(const f32x4*)&cosb[s * 32 + i0];
    f32x4 sv = *(const f32x4*)&sinb[s * 32 + i0];
#pragma unroll
    for (int p = 0; p < 4; ++p) {
        float x0 = bf2f((u16)v[2 * p]);
        float x1 = bf2f((u16)v[2 * p + 1]);
        float r0 = x0 * cv[p] - x1 * sv[p];
        float r1 = x0 * sv[p] + x1 * cv[p];
        v[2 * p] = (short)f2bf(r0);
        v[2 * p + 1] = (short)f2bf(r1);
    }
    *(short8*)&t[base] = v;
}

// ---------------- causal GQA flash attention ----------------
// grid (qt=16, h=32, b=4), 4 waves; wave wid owns q rows qt*64+wid*16..+15.
// Swapped QK^T (S^T = mfma(K,Q)) -> lane-local softmax. K and V^T tiles staged in
// double-buffered padded LDS with async split: issue loads -> compute -> write -> barrier.
__global__ __launch_bounds__(256) void attn_kernel(
    const u16* __restrict__ q, const u16* __restrict__ k, const u16* __restrict__ vt,
    u16* __restrict__ ctx) {
    __shared__ u16 Ks[2][64 * 72];
    __shared__ u16 Vs[2][64 * 72];   // Vs[d][kv]
    const int qt = blockIdx.x, h = blockIdx.y, b = blockIdx.z;
    const int g = h >> 2;
    const int tid = threadIdx.x, wid = tid >> 6, lane = tid & 63;
    const int fr = lane & 15, hi = lane >> 4, fk = hi * 8;
    const int qrow0 = qt * 64 + wid * 16;
    const int sq = qrow0 + fr;
    short8 qf[2];
    {
        const u16* qp = &q[((size_t)(b * 1024 + sq)) * 2048 + h * 64];
        qf[0] = *(const short8*)&qp[fk];
        qf[1] = *(const short8*)&qp[32 + fk];
    }
    f32x4 o[4] = {};
    float m = -3.0e38f, l = 0.0f;
    // staging geometry: 64x64 tile, 512 chunks of 8 elems; thread does chunks tid, tid+256
    const int r0 = tid >> 3, c0 = (tid & 7) * 8;       // r0 in 0..31
    const u16* kbase = k + ((size_t)b * 1024) * 512 + g * 64;
    const u16* vbase = vt + ((size_t)(g * 64)) * 4096 + b * 1024;
    const int srcA = fr | ((2 * (hi & 1)) << 4);
    const int srcB = srcA + 16;

    auto stage_load = [&](int kt, short8& k0, short8& k1, short8& v0, short8& v1) {
        const u16* kg = kbase + (size_t)(kt * 64) * 512;
        const u16* vg = vbase + kt * 64;
        k0 = *(const short8*)&kg[(size_t)r0 * 512 + c0];
        k1 = *(const short8*)&kg[(size_t)(r0 + 32) * 512 + c0];
        v0 = *(const short8*)&vg[(size_t)r0 * 4096 + c0];
        v1 = *(const short8*)&vg[(size_t)(r0 + 32) * 4096 + c0];
    };
    auto stage_write = [&](int buf, short8 k0, short8 k1, short8 v0, short8 v1) {
        *(short8*)&Ks[buf][r0 * 72 + c0] = k0;
        *(short8*)&Ks[buf][(r0 + 32) * 72 + c0] = k1;
        *(short8*)&Vs[buf][r0 * 72 + c0] = v0;
        *(short8*)&Vs[buf][(r0 + 32) * 72 + c0] = v1;
    };

    {
        short8 a, bb, c, d;
        stage_load(0, a, bb, c, d);
        stage_write(0, a, bb, c, d);
    }
    __syncthreads();

    for (int kt = 0; kt <= qt; ++kt) {
        const int cur = kt & 1;
        const bool more = (kt < qt);
        short8 nk0, nk1, nv0, nv1;
        if (more) stage_load(kt + 1, nk0, nk1, nv0, nv1);

        const bool diag = (kt == qt);
        const int miq = diag ? wid : 3;
        f32x4 s[4];
#pragma unroll
        for (int mi = 0; mi < 4; ++mi) {
            if (mi <= miq) {
                short8 kf0 = *(const short8*)&Ks[cur][(mi * 16 + fr) * 72 + fk];
                short8 kf1 = *(const short8*)&Ks[cur][(mi * 16 + fr) * 72 + 32 + fk];
                f32x4 z = {};
                z = mfma16(kf0, qf[0], z);
                z = mfma16(kf1, qf[1], z);
#pragma unroll
                for (int j = 0; j < 4; ++j) {
                    float val = z[j] * SCL2;
                    if (diag && (kt * 64 + mi * 16 + hi * 4 + j > sq)) val = -3.0e38f;
                    s[mi][j] = val;
                }
            } else {
                s[mi][0] = -3.0e38f; s[mi][1] = -3.0e38f;
                s[mi][2] = -3.0e38f; s[mi][3] = -3.0e38f;
            }
        }
        float pmax = fmaxf(fmaxf(fmaxf(s[0][0], s[0][1]), fmaxf(s[0][2], s[0][3])),
                           fmaxf(fmaxf(s[1][0], s[1][1]), fmaxf(s[1][2], s[1][3])));
        pmax = fmaxf(pmax, fmaxf(fmaxf(fmaxf(s[2][0], s[2][1]), fmaxf(s[2][2], s[2][3])),
                                 fmaxf(fmaxf(s[3][0], s[3][1]), fmaxf(s[3][2], s[3][3]))));
        pmax = fmaxf(pmax, __shfl_xor(pmax, 16));
        pmax = fmaxf(pmax, __shfl_xor(pmax, 32));
        const float mnew = fmaxf(m, pmax);
        const float fsc = exp2f(m - mnew);
        float rs = 0.0f;
        u32 pk[4][2];
#pragma unroll
        for (int mi = 0; mi < 4; ++mi) {
            float p0 = exp2f(s[mi][0] - mnew);
            float p1 = exp2f(s[mi][1] - mnew);
            float p2 = exp2f(s[mi][2] - mnew);
            float p3 = exp2f(s[mi][3] - mnew);
            rs += (p0 + p1) + (p2 + p3);
            pk[mi][0] = pack2(p0, p1);
            pk[mi][1] = pack2(p2, p3);
        }
        rs += __shfl_xor(rs, 16);
        rs += __shfl_xor(rs, 32);
        l = l * fsc + rs;
        m = mnew;
#pragma unroll
        for (int dn = 0; dn < 4; ++dn)
#pragma unroll
            for (int j = 0; j < 4; ++j) o[dn][j] *= fsc;
        const int ksmax = diag ? (wid >> 1) : 1;
#pragma unroll
        for (int ks = 0; ks < 2; ++ks) {
            if (ks > ksmax) continue;
            u32 a0 = __shfl(pk[2 * ks][0], srcA);
            u32 a1 = __shfl(pk[2 * ks][1], srcA);
            u32 b0 = __shfl(pk[2 * ks][0], srcB);
            u32 b1 = __shfl(pk[2 * ks][1], srcB);
            u32 c0w = __shfl(pk[2 * ks + 1][0], srcA);
            u32 c1 = __shfl(pk[2 * ks + 1][1], srcA);
            u32 d0 = __shfl(pk[2 * ks + 1][0], srcB);
            u32 d1 = __shfl(pk[2 * ks + 1][1], srcB);
            union { u32 w[4]; short8 s8; } pu;
            pu.w[0] = (hi < 2) ? a0 : c0w;
            pu.w[1] = (hi < 2) ? a1 : c1;
            pu.w[2] = (hi < 2) ? b0 : d0;
            pu.w[3] = (hi < 2) ? b1 : d1;
            short8 pf = pu.s8;
#pragma unroll
            for (int dn = 0; dn < 4; ++dn) {
                short8 vf = *(const short8*)&Vs[cur][(dn * 16 + fr) * 72 + ks * 32 + fk];
                o[dn] = mfma16(vf, pf, o[dn]);
            }
        }
        if (more) {
            stage_write(cur ^ 1, nk0, nk1, nv0, nv1);
            __syncthreads();
        }
    }
    const float linv = 1.0f / l;
    const size_t obase = ((size_t)(b * 1024 + sq)) * 2048 + h * 64;
#pragma unroll
    for (int dn = 0; dn < 4; ++dn) {
        u16x4 w;
#pragma unroll
        for (int j = 0; j < 4; ++j) w[j] = f2bf(o[dn][j] * linv);
        *(u16x4*)&ctx[obase + dn * 16 + hi * 4] = w;
    }
}

extern "C" void kernel_launch(void* const* d_in, const int* in_sizes, int n_in,
                              void* d_out, int out_size, void* d_ws, size_t ws_size,
                              hipStream_t stream) {
    const float* x    = (const float*)d_in[0];
    const float* fcos = (const float*)d_in[1];
    const float* fsin = (const float*)d_in[2];
    const float* Wq   = (const float*)d_in[3];
    const float* Wk   = (const float*)d_in[4];
    const float* Wv   = (const float*)d_in[5];
    const float* Wo   = (const float*)d_in[6];
    const float* qA   = (const float*)d_in[7];
    const float* qB   = (const float*)d_in[8];
    const float* kA   = (const float*)d_in[9];
    const float* kB   = (const float*)d_in[10];
    const float* vA   = (const float*)d_in[11];
    const float* vB   = (const float*)d_in[12];
    float* out = (float*)d_out;

    char* ws = (char*)d_ws;
    size_t off = 0;
    auto alloc = [&](size_t bytes) { char* p = ws + off; off += (bytes + 255) & ~(size_t)255; return p; };
    u16* xb   = (u16*)alloc(4096 * 2048 * 2);
    u16* WqT  = (u16*)alloc(2048 * 2048 * 2);
    u16* WkT  = (u16*)alloc(512 * 2048 * 2);
    u16* WvT  = (u16*)alloc(512 * 2048 * 2);
    u16* WoT  = (u16*)alloc(2048 * 2048 * 2);
    u16* qBt  = (u16*)alloc(2048 * 16 * 2);
    u16* kBt  = (u16*)alloc(512 * 16 * 2);
    u16* vBt  = (u16*)alloc(512 * 16 * 2);
    u16* xaq  = (u16*)alloc(4096 * 16 * 2);
    u16* xak  = (u16*)alloc(4096 * 16 * 2);
    u16* xav  = (u16*)alloc(4096 * 16 * 2);
    u16* qbuf = (u16*)alloc(4096 * 2048 * 2);
    u16* kbuf = (u16*)alloc(4096 * 512 * 2);
    u16* VT2  = (u16*)alloc(512 * 4096 * 2);   // V^T: [(g*64+d)][b*1024+s]
    u16* ctx  = (u16*)alloc(4096 * 2048 * 2);

    cast_x_kernel<<<2048, 256, 0, stream>>>(x, xb, 4096 * 2048);

    dim3 tb(32, 32);
    transpose_cast_kernel<<<dim3(64, 64), tb, 0, stream>>>(Wq, WqT, 2048, 2048);
    transpose_cast_kernel<<<dim3(16, 64), tb, 0, stream>>>(Wk, WkT, 2048, 512);
    transpose_cast_kernel<<<dim3(16, 64), tb, 0, stream>>>(Wv, WvT, 2048, 512);
    transpose_cast_kernel<<<dim3(64, 64), tb, 0, stream>>>(Wo, WoT, 2048, 2048);
    transpose_cast_kernel<<<dim3(64, 1), tb, 0, stream>>>(qB, qBt, 16, 2048);
    transpose_cast_kernel<<<dim3(16, 1), tb, 0, stream>>>(kB, kBt, 16, 512);
    transpose_cast_kernel<<<dim3(16, 1), tb, 0, stream>>>(vB, vBt, 16, 512);

    lora_a_kernel<<<4096, 64, 0, stream>>>(x, qA, kA, vA, xaq, xak, xav);

    gemm_kernel<1, 0><<<dim3(32, 16), 256, 0, stream>>>(xb, WqT, qbuf, 2048, xaq, qBt);
    gemm_kernel<1, 0><<<dim3(32, 4), 256, 0, stream>>>(xb, WkT, kbuf, 512, xak, kBt);
    // V computed TRANSPOSED: VT2[feat][b*1024+s] = (x@Wv + LoRA)^T via operand swap
    gemm_kernel<1, 0><<<dim3(4, 32), 256, 0, stream>>>(WvT, xb, VT2, 4096, vBt, xav);

    rope_kernel<<<4096, 256, 0, stream>>>(qbuf, fcos, fsin, 2048, 11);
    rope_kernel<<<1024, 256, 0, stream>>>(kbuf, fcos, fsin, 512, 9);

    attn_kernel<<<dim3(16, 32, 4), 256, 0, stream>>>(qbuf, kbuf, VT2, ctx);

    gemm_kernel<0, 1><<<dim3(32, 16), 256, 0, stream>>>(ctx, WoT, out, 2048, nullptr, nullptr);
}

// Round 4
// 396.172 us; speedup vs baseline: 1.3279x; 1.0588x over previous
//
#include <hip/hip_runtime.h>

typedef unsigned short u16;
typedef unsigned int u32;
typedef __attribute__((ext_vector_type(8))) short short8;
typedef __attribute__((ext_vector_type(4))) float f32x4;
typedef __attribute__((ext_vector_type(4))) u16 u16x4;

#define LOG2E 1.4426950408889634f
#define SCL2 (0.125f * LOG2E)

static __device__ __forceinline__ float bf2f(u16 u) {
    return __uint_as_float(((unsigned)u) << 16);
}
static __device__ __forceinline__ u16 f2bf(float f) {
    unsigned u = __float_as_uint(f);
    unsigned r = (u + 0x7FFF + ((u >> 16) & 1)) >> 16;
    return (u16)r;
}
static __device__ __forceinline__ u32 cvtpk(float lo, float hi) {
    u32 r;
    asm("v_cvt_pk_bf16_f32 %0, %1, %2" : "=v"(r) : "v"(lo), "v"(hi));
    return r;
}
static __device__ __forceinline__ f32x4 mfma16(short8 a, short8 b, f32x4 c) {
    return __builtin_amdgcn_mfma_f32_16x16x32_bf16(a, b, c, 0, 0, 0);
}
static __device__ __forceinline__ void gload_lds16(const void* g, void* l) {
    __builtin_amdgcn_global_load_lds(
        (const __attribute__((address_space(1))) void*)g,
        (__attribute__((address_space(3))) void*)l, 16, 0, 0);
}

// ---------------- cast x (fp32 -> bf16), vectorized ----------------
__global__ void cast_x_kernel(const float* __restrict__ x, u16* __restrict__ xb, int n) {
    int i = (blockIdx.x * blockDim.x + threadIdx.x) * 4;
    int stride = gridDim.x * blockDim.x * 4;
    for (; i < n; i += stride) {
        f32x4 v = *(const f32x4*)&x[i];
        u16x4 o;
        o.x = f2bf(v.x); o.y = f2bf(v.y); o.z = f2bf(v.z); o.w = f2bf(v.w);
        *(u16x4*)&xb[i] = o;
    }
}

// ---------------- transpose + cast: src[R][C] fp32 -> dst[C][R] bf16 ----------------
__global__ void transpose_cast_kernel(const float* __restrict__ src, u16* __restrict__ dst,
                                      int R, int C) {
    __shared__ float tile[32][33];
    int c0 = blockIdx.x * 32, r0 = blockIdx.y * 32;
    int tx = threadIdx.x, ty = threadIdx.y;
    int r = r0 + ty, c = c0 + tx;
    if (r < R && c < C) tile[ty][tx] = src[r * C + c];
    __syncthreads();
    int orow = c0 + ty;
    int oc   = r0 + tx;
    if (orow < C && oc < R) dst[orow * R + oc] = f2bf(tile[tx][ty]);
}

// ---------------- LoRA-A: xa = (x @ A) * 2.0, bf16 out, all 3 adapters ----------------
__global__ __launch_bounds__(64) void lora_a_kernel(
    const float* __restrict__ x,
    const float* __restrict__ qA, const float* __restrict__ kA, const float* __restrict__ vA,
    u16* __restrict__ xaq, u16* __restrict__ xak, u16* __restrict__ xav) {
    const int r = blockIdx.x;
    const int lane = threadIdx.x;
    float aq[16] = {}, ak[16] = {}, av[16] = {};
    const float* xr = x + (size_t)r * 2048;
    for (int kk = lane; kk < 2048; kk += 64) {
        const float xv = xr[kk];
        const f32x4* q4 = (const f32x4*)(qA + kk * 16);
        const f32x4* k4 = (const f32x4*)(kA + kk * 16);
        const f32x4* v4 = (const f32x4*)(vA + kk * 16);
#pragma unroll
        for (int t = 0; t < 4; ++t) {
            f32x4 a = q4[t], b = k4[t], cc = v4[t];
#pragma unroll
            for (int e = 0; e < 4; ++e) {
                aq[t * 4 + e] += xv * a[e];
                ak[t * 4 + e] += xv * b[e];
                av[t * 4 + e] += xv * cc[e];
            }
        }
    }
#pragma unroll
    for (int j = 0; j < 16; ++j) {
#pragma unroll
        for (int off = 1; off < 64; off <<= 1) {
            aq[j] += __shfl_xor(aq[j], off);
            ak[j] += __shfl_xor(ak[j], off);
            av[j] += __shfl_xor(av[j], off);
        }
    }
    if (lane == 0) {
#pragma unroll
        for (int j = 0; j < 16; ++j) {
            xaq[r * 16 + j] = f2bf(aq[j] * 2.0f);
            xak[r * 16 + j] = f2bf(ak[j] * 2.0f);
            xav[r * 16 + j] = f2bf(av[j] * 2.0f);
        }
    }
}

// ---------------- GEMM (m97 recipe + XCD swizzle) ----------------
template <int LORA, int OUTF32>
__global__ __launch_bounds__(256) void gemm_kernel(
    const u16* __restrict__ A, const u16* __restrict__ Bt, void* __restrict__ Cout, int Nn,
    const u16* __restrict__ xa, const u16* __restrict__ LBt) {
    constexpr int K = 2048;
    __shared__ u16 As[128 * 64];
    __shared__ u16 Bs[128 * 64];
    const int tid = threadIdx.x;
    const int wid = tid >> 6, lane = tid & 63;
    // bijective XCD swizzle (nwg always divisible by 8 in our launches)
    const int nwg = gridDim.x * gridDim.y;
    int flat = blockIdx.y * gridDim.x + blockIdx.x;
    flat = (flat & 7) * (nwg >> 3) + (flat >> 3);
    const int mbase = (flat % gridDim.x) * 128;
    const int nbase = (flat / gridDim.x) * 128;
    const int wrow = (wid >> 1) * 64, wcol = (wid & 1) * 64;
    const int fr = lane & 15, fk = (lane >> 4) * 8;
    const int l8 = lane >> 3, c8 = (lane & 7) * 8;
    f32x4 acc[4][4] = {};
    const u16* Ag = A + (size_t)mbase * K;
    const u16* Bg = Bt + (size_t)nbase * K;
    for (int kt = 0; kt < K; kt += 64) {
        __syncthreads();
#pragma unroll
        for (int i = 0; i < 4; ++i) {
            const int r8 = (i * 4 + wid) * 8;
            gload_lds16(&Ag[(size_t)(r8 + l8) * K + kt + c8], &As[r8 * 64]);
            gload_lds16(&Bg[(size_t)(r8 + l8) * K + kt + c8], &Bs[r8 * 64]);
        }
        __syncthreads();
#pragma unroll
        for (int ks = 0; ks < 2; ++ks) {
            short8 af[4], bfr[4];
#pragma unroll
            for (int i = 0; i < 4; ++i) {
                af[i]  = *(const short8*)&As[(wrow + i * 16 + fr) * 64 + ks * 32 + fk];
                bfr[i] = *(const short8*)&Bs[(wcol + i * 16 + fr) * 64 + ks * 32 + fk];
            }
#pragma unroll
            for (int mi = 0; mi < 4; ++mi)
#pragma unroll
                for (int ni = 0; ni < 4; ++ni)
                    acc[mi][ni] = mfma16(af[mi], bfr[ni], acc[mi][ni]);
        }
    }
    if (LORA) {
        const int rr = tid >> 1, hh = (tid & 1) * 8;
        short8 xv = *(const short8*)&xa[(mbase + rr) * 16 + hh];
        short8 lv = *(const short8*)&LBt[(nbase + rr) * 16 + hh];
        short8 z = {};
        __syncthreads();
        *(short8*)&As[rr * 64 + hh] = xv;
        *(short8*)&As[rr * 64 + 16 + hh] = z;
        *(short8*)&Bs[rr * 64 + hh] = lv;
        *(short8*)&Bs[rr * 64 + 16 + hh] = z;
        __syncthreads();
        short8 af[4], bfr[4];
#pragma unroll
        for (int i = 0; i < 4; ++i) {
            af[i]  = *(const short8*)&As[(wrow + i * 16 + fr) * 64 + fk];
            bfr[i] = *(const short8*)&Bs[(wcol + i * 16 + fr) * 64 + fk];
        }
#pragma unroll
        for (int mi = 0; mi < 4; ++mi)
#pragma unroll
            for (int ni = 0; ni < 4; ++ni)
                acc[mi][ni] = mfma16(af[mi], bfr[ni], acc[mi][ni]);
    }
    const int rb = mbase + wrow + ((lane >> 4) << 2);
    const int cb = nbase + wcol + fr;
    if (OUTF32) {
        float* C = (float*)Cout;
#pragma unroll
        for (int mi = 0; mi < 4; ++mi)
#pragma unroll
            for (int j = 0; j < 4; ++j) {
                const size_t ro = (size_t)(rb + mi * 16 + j) * Nn;
#pragma unroll
                for (int ni = 0; ni < 4; ++ni) C[ro + cb + ni * 16] = acc[mi][ni][j];
            }
    } else {
        u16* C = (u16*)Cout;
#pragma unroll
        for (int mi = 0; mi < 4; ++mi)
#pragma unroll
            for (int j = 0; j < 4; ++j) {
                const size_t ro = (size_t)(rb + mi * 16 + j) * Nn;
#pragma unroll
                for (int ni = 0; ni < 4; ++ni) C[ro + cb + ni * 16] = f2bf(acc[mi][ni][j]);
            }
    }
}

// ---------------- RoPE in place on bf16 [4096][width] ----------------
__global__ void rope_kernel(u16* __restrict__ t, const float* __restrict__ cosb,
                            const float* __restrict__ sinb, int width, int shift) {
    int idx = blockIdx.x * blockDim.x + threadIdx.x;
    int base = idx * 8;
    int row = base >> shift;
    int within = base & (width - 1);
    int d0 = within & 63;
    int i0 = d0 >> 1;
    int s = row & 1023;
    short8 v = *(short8*)&t[base];
    f32x4 cv = *(const f32x4*)&cosb[s * 32 + i0];
    f32x4 sv = *(const f32x4*)&sinb[s * 32 + i0];
#pragma unroll
    for (int p = 0; p < 4; ++p) {
        float x0 = bf2f((u16)v[2 * p]);
        float x1 = bf2f((u16)v[2 * p + 1]);
        float r0 = x0 * cv[p] - x1 * sv[p];
        float r1 = x0 * sv[p] + x1 * cv[p];
        v[2 * p] = (short)f2bf(r0);
        v[2 * p + 1] = (short)f2bf(r1);
    }
    *(short8*)&t[base] = v;
}

// ---------------- attention tile step (diag specialization + defer-max + cvt_pk) --------
template <bool DIAG>
static __device__ __forceinline__ void attn_tile_step(
    const u16* __restrict__ Ksb, const u16* __restrict__ Vsb,
    const short8* qf, f32x4* o, float& m, float& l,
    int sq, int kt, int wid, int fr, int hi, int fk, int srcA, int srcB) {
    f32x4 s[4];
    const int kvb = kt * 64;
#pragma unroll
    for (int mi = 0; mi < 4; ++mi) {
        if (!DIAG || mi <= wid) {
            short8 kf0 = *(const short8*)&Ksb[(mi * 16 + fr) * 72 + fk];
            short8 kf1 = *(const short8*)&Ksb[(mi * 16 + fr) * 72 + 32 + fk];
            f32x4 z = {};
            z = mfma16(kf0, qf[0], z);
            z = mfma16(kf1, qf[1], z);
#pragma unroll
            for (int j = 0; j < 4; ++j) {
                float val = z[j] * SCL2;
                if (DIAG && mi == wid && (kvb + mi * 16 + hi * 4 + j > sq)) val = -3.0e38f;
                s[mi][j] = val;
            }
        } else {
            s[mi][0] = -3.0e38f; s[mi][1] = -3.0e38f;
            s[mi][2] = -3.0e38f; s[mi][3] = -3.0e38f;
        }
    }
    float pmax = fmaxf(fmaxf(fmaxf(s[0][0], s[0][1]), fmaxf(s[0][2], s[0][3])),
                       fmaxf(fmaxf(s[1][0], s[1][1]), fmaxf(s[1][2], s[1][3])));
    pmax = fmaxf(pmax, fmaxf(fmaxf(fmaxf(s[2][0], s[2][1]), fmaxf(s[2][2], s[2][3])),
                             fmaxf(fmaxf(s[3][0], s[3][1]), fmaxf(s[3][2], s[3][3]))));
    pmax = fmaxf(pmax, __shfl_xor(pmax, 16));
    pmax = fmaxf(pmax, __shfl_xor(pmax, 32));
    // defer-max (T13): only rescale when the running max grows by > 8 (log2 domain)
    if (__any(pmax > m + 8.0f)) {
        const float mnew = fmaxf(m, pmax);
        const float fsc = exp2f(m - mnew);
        l *= fsc;
        m = mnew;
#pragma unroll
        for (int dn = 0; dn < 4; ++dn)
#pragma unroll
            for (int j = 0; j < 4; ++j) o[dn][j] *= fsc;
    }
    float rs = 0.0f;
    u32 pk[4][2];
#pragma unroll
    for (int mi = 0; mi < 4; ++mi) {
        float p0 = exp2f(s[mi][0] - m);
        float p1 = exp2f(s[mi][1] - m);
        float p2 = exp2f(s[mi][2] - m);
        float p3 = exp2f(s[mi][3] - m);
        rs += (p0 + p1) + (p2 + p3);
        pk[mi][0] = cvtpk(p0, p1);
        pk[mi][1] = cvtpk(p2, p3);
    }
    rs += __shfl_xor(rs, 16);
    rs += __shfl_xor(rs, 32);
    l += rs;
    const int ksmax = DIAG ? (wid >> 1) : 1;
#pragma unroll
    for (int ks = 0; ks < 2; ++ks) {
        if (ks > ksmax) continue;
        u32 a0 = __shfl(pk[2 * ks][0], srcA);
        u32 a1 = __shfl(pk[2 * ks][1], srcA);
        u32 b0 = __shfl(pk[2 * ks][0], srcB);
        u32 b1 = __shfl(pk[2 * ks][1], srcB);
        u32 c0w = __shfl(pk[2 * ks + 1][0], srcA);
        u32 c1 = __shfl(pk[2 * ks + 1][1], srcA);
        u32 d0 = __shfl(pk[2 * ks + 1][0], srcB);
        u32 d1 = __shfl(pk[2 * ks + 1][1], srcB);
        union { u32 w[4]; short8 s8; } pu;
        pu.w[0] = (hi < 2) ? a0 : c0w;
        pu.w[1] = (hi < 2) ? a1 : c1;
        pu.w[2] = (hi < 2) ? b0 : d0;
        pu.w[3] = (hi < 2) ? b1 : d1;
        short8 pf = pu.s8;
#pragma unroll
        for (int dn = 0; dn < 4; ++dn) {
            short8 vf = *(const short8*)&Vsb[(dn * 16 + fr) * 72 + ks * 32 + fk];
            o[dn] = mfma16(vf, pf, o[dn]);
        }
    }
}

// ---------------- causal GQA flash attention, paired q-tiles for load balance ----------
// grid (jp=8, h=32, b=4); block handles q-tiles qtA=jp and qtB=15-jp (17 tile-computations
// each). 4 waves; wave wid owns rows +wid*16..+15 of each q-tile. K/V^T staged in
// double-buffered LDS, async-split; staging shared by both q-tiles for kt<=qtA.
__global__ __launch_bounds__(256) void attn_kernel(
    const u16* __restrict__ q, const u16* __restrict__ k, const u16* __restrict__ vt,
    u16* __restrict__ ctx) {
    __shared__ u16 Ks[2][64 * 72];
    __shared__ u16 Vs[2][64 * 72];
    const int jp = blockIdx.x, h = blockIdx.y, b = blockIdx.z;
    const int qtA = jp, qtB = 15 - jp;
    const int g = h >> 2;
    const int tid = threadIdx.x, wid = tid >> 6, lane = tid & 63;
    const int fr = lane & 15, hi = lane >> 4, fk = hi * 8;
    const int sqA = qtA * 64 + wid * 16 + fr;
    const int sqB = qtB * 64 + wid * 16 + fr;
    short8 qfA[2], qfB[2];
    {
        const u16* qp = &q[((size_t)(b * 1024 + sqA)) * 2048 + h * 64];
        qfA[0] = *(const short8*)&qp[fk];
        qfA[1] = *(const short8*)&qp[32 + fk];
        const u16* qp2 = &q[((size_t)(b * 1024 + sqB)) * 2048 + h * 64];
        qfB[0] = *(const short8*)&qp2[fk];
        qfB[1] = *(const short8*)&qp2[32 + fk];
    }
    f32x4 oA[4] = {}, oB[4] = {};
    float mA = -3.0e38f, lA = 0.0f, mB = -3.0e38f, lB = 0.0f;
    const int r0 = tid >> 3, c0 = (tid & 7) * 8;
    const u16* kbase = k + ((size_t)b * 1024) * 512 + g * 64;
    const u16* vbase = vt + ((size_t)(g * 64)) * 4096 + b * 1024;
    const int srcA = fr | ((2 * (hi & 1)) << 4);
    const int srcB = srcA + 16;

    auto stage_load = [&](int kt, short8& k0, short8& k1, short8& v0, short8& v1) {
        const u16* kg = kbase + (size_t)(kt * 64) * 512;
        const u16* vg = vbase + kt * 64;
        k0 = *(const short8*)&kg[(size_t)r0 * 512 + c0];
        k1 = *(const short8*)&kg[(size_t)(r0 + 32) * 512 + c0];
        v0 = *(const short8*)&vg[(size_t)r0 * 4096 + c0];
        v1 = *(const short8*)&vg[(size_t)(r0 + 32) * 4096 + c0];
    };
    auto stage_write = [&](int buf, short8 k0, short8 k1, short8 v0, short8 v1) {
        *(short8*)&Ks[buf][r0 * 72 + c0] = k0;
        *(short8*)&Ks[buf][(r0 + 32) * 72 + c0] = k1;
        *(short8*)&Vs[buf][r0 * 72 + c0] = v0;
        *(short8*)&Vs[buf][(r0 + 32) * 72 + c0] = v1;
    };

    {
        short8 a, bb, c, d;
        stage_load(0, a, bb, c, d);
        stage_write(0, a, bb, c, d);
    }
    __syncthreads();

    for (int kt = 0; kt <= qtB; ++kt) {
        const int cur = kt & 1;
        const bool more = (kt < qtB);
        short8 nk0, nk1, nv0, nv1;
        if (more) stage_load(kt + 1, nk0, nk1, nv0, nv1);

        if (kt < qtA)
            attn_tile_step<false>(Ks[cur], Vs[cur], qfA, oA, mA, lA, sqA, kt, wid, fr, hi, fk, srcA, srcB);
        else if (kt == qtA)
            attn_tile_step<true>(Ks[cur], Vs[cur], qfA, oA, mA, lA, sqA, kt, wid, fr, hi, fk, srcA, srcB);
        if (kt < qtB)
            attn_tile_step<false>(Ks[cur], Vs[cur], qfB, oB, mB, lB, sqB, kt, wid, fr, hi, fk, srcA, srcB);
        else
            attn_tile_step<true>(Ks[cur], Vs[cur], qfB, oB, mB, lB, sqB, kt, wid, fr, hi, fk, srcA, srcB);

        if (more) {
            stage_write(cur ^ 1, nk0, nk1, nv0, nv1);
            __syncthreads();
        }
    }
    {
        const float linv = 1.0f / lA;
        const size_t obase = ((size_t)(b * 1024 + sqA)) * 2048 + h * 64;
#pragma unroll
        for (int dn = 0; dn < 4; ++dn) {
            u16x4 w;
#pragma unroll
            for (int j = 0; j < 4; ++j) w[j] = f2bf(oA[dn][j] * linv);
            *(u16x4*)&ctx[obase + dn * 16 + hi * 4] = w;
        }
    }
    {
        const float linv = 1.0f / lB;
        const size_t obase = ((size_t)(b * 1024 + sqB)) * 2048 + h * 64;
#pragma unroll
        for (int dn = 0; dn < 4; ++dn) {
            u16x4 w;
#pragma unroll
            for (int j = 0; j < 4; ++j) w[j] = f2bf(oB[dn][j] * linv);
            *(u16x4*)&ctx[obase + dn * 16 + hi * 4] = w;
        }
    }
}

extern "C" void kernel_launch(void* const* d_in, const int* in_sizes, int n_in,
                              void* d_out, int out_size, void* d_ws, size_t ws_size,
                              hipStream_t stream) {
    const float* x    = (const float*)d_in[0];
    const float* fcos = (const float*)d_in[1];
    const float* fsin = (const float*)d_in[2];
    const float* Wq   = (const float*)d_in[3];
    const float* Wk   = (const float*)d_in[4];
    const float* Wv   = (const float*)d_in[5];
    const float* Wo   = (const float*)d_in[6];
    const float* qA   = (const float*)d_in[7];
    const float* qB   = (const float*)d_in[8];
    const float* kA   = (const float*)d_in[9];
    const float* kB   = (const float*)d_in[10];
    const float* vA   = (const float*)d_in[11];
    const float* vB   = (const float*)d_in[12];
    float* out = (float*)d_out;

    char* ws = (char*)d_ws;
    size_t off = 0;
    auto alloc = [&](size_t bytes) { char* p = ws + off; off += (bytes + 255) & ~(size_t)255; return p; };
    u16* xb   = (u16*)alloc(4096 * 2048 * 2);
    u16* WqT  = (u16*)alloc(2048 * 2048 * 2);
    u16* WkT  = (u16*)alloc(512 * 2048 * 2);
    u16* WvT  = (u16*)alloc(512 * 2048 * 2);
    u16* WoT  = (u16*)alloc(2048 * 2048 * 2);
    u16* qBt  = (u16*)alloc(2048 * 16 * 2);
    u16* kBt  = (u16*)alloc(512 * 16 * 2);
    u16* vBt  = (u16*)alloc(512 * 16 * 2);
    u16* xaq  = (u16*)alloc(4096 * 16 * 2);
    u16* xak  = (u16*)alloc(4096 * 16 * 2);
    u16* xav  = (u16*)alloc(4096 * 16 * 2);
    u16* qbuf = (u16*)alloc(4096 * 2048 * 2);
    u16* kbuf = (u16*)alloc(4096 * 512 * 2);
    u16* VT2  = (u16*)alloc(512 * 4096 * 2);   // V^T: [(g*64+d)][b*1024+s]
    u16* ctx  = (u16*)alloc(4096 * 2048 * 2);

    cast_x_kernel<<<2048, 256, 0, stream>>>(x, xb, 4096 * 2048);

    dim3 tb(32, 32);
    transpose_cast_kernel<<<dim3(64, 64), tb, 0, stream>>>(Wq, WqT, 2048, 2048);
    transpose_cast_kernel<<<dim3(16, 64), tb, 0, stream>>>(Wk, WkT, 2048, 512);
    transpose_cast_kernel<<<dim3(16, 64), tb, 0, stream>>>(Wv, WvT, 2048, 512);
    transpose_cast_kernel<<<dim3(64, 64), tb, 0, stream>>>(Wo, WoT, 2048, 2048);
    transpose_cast_kernel<<<dim3(64, 1), tb, 0, stream>>>(qB, qBt, 16, 2048);
    transpose_cast_kernel<<<dim3(16, 1), tb, 0, stream>>>(kB, kBt, 16, 512);
    transpose_cast_kernel<<<dim3(16, 1), tb, 0, stream>>>(vB, vBt, 16, 512);

    lora_a_kernel<<<4096, 64, 0, stream>>>(x, qA, kA, vA, xaq, xak, xav);

    gemm_kernel<1, 0><<<dim3(32, 16), 256, 0, stream>>>(xb, WqT, qbuf, 2048, xaq, qBt);
    gemm_kernel<1, 0><<<dim3(32, 4), 256, 0, stream>>>(xb, WkT, kbuf, 512, xak, kBt);
    // V computed TRANSPOSED: VT2[feat][b*1024+s] = (x@Wv + LoRA)^T via operand swap
    gemm_kernel<1, 0><<<dim3(4, 32), 256, 0, stream>>>(WvT, xb, VT2, 4096, vBt, xav);

    rope_kernel<<<4096, 256, 0, stream>>>(qbuf, fcos, fsin, 2048, 11);
    rope_kernel<<<1024, 256, 0, stream>>>(kbuf, fcos, fsin, 512, 9);

    attn_kernel<<<dim3(8, 32, 4), 256, 0, stream>>>(qbuf, kbuf, VT2, ctx);

    gemm_kernel<0, 1><<<dim3(32, 16), 256, 0, stream>>>(ctx, WoT, out, 2048, nullptr, nullptr);
}

// Round 5
// 305.888 us; speedup vs baseline: 1.7198x; 1.2952x over previous
//
#include <hip/hip_runtime.h>

typedef unsigned short u16;
typedef unsigned int u32;
typedef __attribute__((ext_vector_type(8))) short short8;
typedef __attribute__((ext_vector_type(4))) float f32x4;
typedef __attribute__((ext_vector_type(4))) u16 u16x4;

#define LOG2E 1.4426950408889634f
#define SCL2 (0.125f * LOG2E)

static __device__ __forceinline__ float bf2f(u16 u) {
    return __uint_as_float(((unsigned)u) << 16);
}
static __device__ __forceinline__ u16 f2bf(float f) {
    unsigned u = __float_as_uint(f);
    unsigned r = (u + 0x7FFF + ((u >> 16) & 1)) >> 16;
    return (u16)r;
}
static __device__ __forceinline__ u32 cvtpk(float lo, float hi) {
    u32 r;
    asm("v_cvt_pk_bf16_f32 %0, %1, %2" : "=v"(r) : "v"(lo), "v"(hi));
    return r;
}
static __device__ __forceinline__ f32x4 mfma16(short8 a, short8 b, f32x4 c) {
    return __builtin_amdgcn_mfma_f32_16x16x32_bf16(a, b, c, 0, 0, 0);
}
static __device__ __forceinline__ void gload_lds16(const void* g, void* l) {
    __builtin_amdgcn_global_load_lds(
        (const __attribute__((address_space(1))) void*)g,
        (__attribute__((address_space(3))) void*)l, 16, 0, 0);
}

// ---------------- cast x (fp32 -> bf16), vectorized ----------------
__global__ void cast_x_kernel(const float* __restrict__ x, u16* __restrict__ xb, int n) {
    int i = (blockIdx.x * blockDim.x + threadIdx.x) * 4;
    int stride = gridDim.x * blockDim.x * 4;
    for (; i < n; i += stride) {
        f32x4 v = *(const f32x4*)&x[i];
        u16x4 o;
        o.x = f2bf(v.x); o.y = f2bf(v.y); o.z = f2bf(v.z); o.w = f2bf(v.w);
        *(u16x4*)&xb[i] = o;
    }
}

// ---------------- transpose + cast: src[R][C] fp32 -> dst[C][R] bf16 ----------------
__global__ void transpose_cast_kernel(const float* __restrict__ src, u16* __restrict__ dst,
                                      int R, int C) {
    __shared__ float tile[32][33];
    int c0 = blockIdx.x * 32, r0 = blockIdx.y * 32;
    int tx = threadIdx.x, ty = threadIdx.y;
    tile[ty][tx] = src[(size_t)(r0 + ty) * C + c0 + tx];
    __syncthreads();
    dst[(size_t)(c0 + ty) * R + r0 + tx] = f2bf(tile[tx][ty]);
}

// ---------------- fused LoRA weight fold + transpose + cast ----------------
// dst[C][R] bf16 = (W[R][C] + 2 * A[R][16] @ Bm[16][C])^T  (R,C multiples of 32)
__global__ void fused_wT_kernel(const float* __restrict__ W, const float* __restrict__ A,
                                const float* __restrict__ Bm, u16* __restrict__ dst,
                                int R, int C) {
    __shared__ float tile[32][33];
    __shared__ float As[32][17];
    __shared__ float Bs[16][33];
    int c0 = blockIdx.x * 32, r0 = blockIdx.y * 32;
    int tx = threadIdx.x, ty = threadIdx.y;
    tile[ty][tx] = W[(size_t)(r0 + ty) * C + c0 + tx];
    if (tx < 16) As[ty][tx] = A[(r0 + ty) * 16 + tx];
    if (ty < 16) Bs[ty][tx] = Bm[(size_t)ty * C + c0 + tx];
    __syncthreads();
    float acc = 0.0f;
#pragma unroll
    for (int rr = 0; rr < 16; ++rr) acc += As[tx][rr] * Bs[rr][ty];
    dst[(size_t)(c0 + ty) * R + r0 + tx] = f2bf(tile[tx][ty] + 2.0f * acc);
}

// ---------------- GEMM (m97 recipe + XCD swizzle) ----------------
// C[M][Nn] = A[M][2048] @ Bt[Nn][2048]^T
template <int OUTF32>
__global__ __launch_bounds__(256) void gemm_kernel(
    const u16* __restrict__ A, const u16* __restrict__ Bt, void* __restrict__ Cout, int Nn) {
    constexpr int K = 2048;
    __shared__ u16 As[128 * 64];
    __shared__ u16 Bs[128 * 64];
    const int tid = threadIdx.x;
    const int wid = tid >> 6, lane = tid & 63;
    const int nwg = gridDim.x * gridDim.y;
    int flat = blockIdx.y * gridDim.x + blockIdx.x;
    flat = (flat & 7) * (nwg >> 3) + (flat >> 3);
    const int mbase = (flat % gridDim.x) * 128;
    const int nbase = (flat / gridDim.x) * 128;
    const int wrow = (wid >> 1) * 64, wcol = (wid & 1) * 64;
    const int fr = lane & 15, fk = (lane >> 4) * 8;
    const int l8 = lane >> 3, c8 = (lane & 7) * 8;
    f32x4 acc[4][4] = {};
    const u16* Ag = A + (size_t)mbase * K;
    const u16* Bg = Bt + (size_t)nbase * K;
    for (int kt = 0; kt < K; kt += 64) {
        __syncthreads();
#pragma unroll
        for (int i = 0; i < 4; ++i) {
            const int r8 = (i * 4 + wid) * 8;
            gload_lds16(&Ag[(size_t)(r8 + l8) * K + kt + c8], &As[r8 * 64]);
            gload_lds16(&Bg[(size_t)(r8 + l8) * K + kt + c8], &Bs[r8 * 64]);
        }
        __syncthreads();
#pragma unroll
        for (int ks = 0; ks < 2; ++ks) {
            short8 af[4], bfr[4];
#pragma unroll
            for (int i = 0; i < 4; ++i) {
                af[i]  = *(const short8*)&As[(wrow + i * 16 + fr) * 64 + ks * 32 + fk];
                bfr[i] = *(const short8*)&Bs[(wcol + i * 16 + fr) * 64 + ks * 32 + fk];
            }
#pragma unroll
            for (int mi = 0; mi < 4; ++mi)
#pragma unroll
                for (int ni = 0; ni < 4; ++ni)
                    acc[mi][ni] = mfma16(af[mi], bfr[ni], acc[mi][ni]);
        }
    }
    const int rb = mbase + wrow + ((lane >> 4) << 2);
    const int cb = nbase + wcol + fr;
    if (OUTF32) {
        float* C = (float*)Cout;
#pragma unroll
        for (int mi = 0; mi < 4; ++mi)
#pragma unroll
            for (int j = 0; j < 4; ++j) {
                const size_t ro = (size_t)(rb + mi * 16 + j) * Nn;
#pragma unroll
                for (int ni = 0; ni < 4; ++ni) C[ro + cb + ni * 16] = acc[mi][ni][j];
            }
    } else {
        u16* C = (u16*)Cout;
#pragma unroll
        for (int mi = 0; mi < 4; ++mi)
#pragma unroll
            for (int j = 0; j < 4; ++j) {
                const size_t ro = (size_t)(rb + mi * 16 + j) * Nn;
#pragma unroll
                for (int ni = 0; ni < 4; ++ni) C[ro + cb + ni * 16] = f2bf(acc[mi][ni][j]);
            }
    }
}

// ---------------- RoPE in place on bf16 [4096][width] ----------------
__global__ void rope_kernel(u16* __restrict__ t, const float* __restrict__ cosb,
                            const float* __restrict__ sinb, int width, int shift) {
    int idx = blockIdx.x * blockDim.x + threadIdx.x;
    int base = idx * 8;
    int row = base >> shift;
    int within = base & (width - 1);
    int d0 = within & 63;
    int i0 = d0 >> 1;
    int s = row & 1023;
    short8 v = *(short8*)&t[base];
    f32x4 cv = *(const f32x4*)&cosb[s * 32 + i0];
    f32x4 sv = *(const f32x4*)&sinb[s * 32 + i0];
#pragma unroll
    for (int p = 0; p < 4; ++p) {
        float x0 = bf2f((u16)v[2 * p]);
        float x1 = bf2f((u16)v[2 * p + 1]);
        float r0 = x0 * cv[p] - x1 * sv[p];
        float r1 = x0 * sv[p] + x1 * cv[p];
        v[2 * p] = (short)f2bf(r0);
        v[2 * p + 1] = (short)f2bf(r1);
    }
    *(short8*)&t[base] = v;
}

// ---------------- attention tile step (diag specialization + defer-max + cvt_pk) --------
template <bool DIAG>
static __device__ __forceinline__ void attn_tile_step(
    const u16* __restrict__ Ksb, const u16* __restrict__ Vsb,
    const short8* qf, f32x4* o, float& m, float& l,
    int sq, int kt, int wid, int fr, int hi, int fk, int srcA, int srcB) {
    f32x4 s[4];
    const int kvb = kt * 64;
#pragma unroll
    for (int mi = 0; mi < 4; ++mi) {
        if (!DIAG || mi <= wid) {
            short8 kf0 = *(const short8*)&Ksb[(mi * 16 + fr) * 72 + fk];
            short8 kf1 = *(const short8*)&Ksb[(mi * 16 + fr) * 72 + 32 + fk];
            f32x4 z = {};
            z = mfma16(kf0, qf[0], z);
            z = mfma16(kf1, qf[1], z);
#pragma unroll
            for (int j = 0; j < 4; ++j) {
                float val = z[j] * SCL2;
                if (DIAG && mi == wid && (kvb + mi * 16 + hi * 4 + j > sq)) val = -3.0e38f;
                s[mi][j] = val;
            }
        } else {
            s[mi][0] = -3.0e38f; s[mi][1] = -3.0e38f;
            s[mi][2] = -3.0e38f; s[mi][3] = -3.0e38f;
        }
    }
    float pmax = fmaxf(fmaxf(fmaxf(s[0][0], s[0][1]), fmaxf(s[0][2], s[0][3])),
                       fmaxf(fmaxf(s[1][0], s[1][1]), fmaxf(s[1][2], s[1][3])));
    pmax = fmaxf(pmax, fmaxf(fmaxf(fmaxf(s[2][0], s[2][1]), fmaxf(s[2][2], s[2][3])),
                             fmaxf(fmaxf(s[3][0], s[3][1]), fmaxf(s[3][2], s[3][3]))));
    pmax = fmaxf(pmax, __shfl_xor(pmax, 16));
    pmax = fmaxf(pmax, __shfl_xor(pmax, 32));
    if (__any(pmax > m + 8.0f)) {
        const float mnew = fmaxf(m, pmax);
        const float fsc = exp2f(m - mnew);
        l *= fsc;
        m = mnew;
#pragma unroll
        for (int dn = 0; dn < 4; ++dn)
#pragma unroll
            for (int j = 0; j < 4; ++j) o[dn][j] *= fsc;
    }
    float rs = 0.0f;
    u32 pk[4][2];
#pragma unroll
    for (int mi = 0; mi < 4; ++mi) {
        float p0 = exp2f(s[mi][0] - m);
        float p1 = exp2f(s[mi][1] - m);
        float p2 = exp2f(s[mi][2] - m);
        float p3 = exp2f(s[mi][3] - m);
        rs += (p0 + p1) + (p2 + p3);
        pk[mi][0] = cvtpk(p0, p1);
        pk[mi][1] = cvtpk(p2, p3);
    }
    rs += __shfl_xor(rs, 16);
    rs += __shfl_xor(rs, 32);
    l += rs;
    const int ksmax = DIAG ? (wid >> 1) : 1;
#pragma unroll
    for (int ks = 0; ks < 2; ++ks) {
        if (ks > ksmax) continue;
        u32 a0 = __shfl(pk[2 * ks][0], srcA);
        u32 a1 = __shfl(pk[2 * ks][1], srcA);
        u32 b0 = __shfl(pk[2 * ks][0], srcB);
        u32 b1 = __shfl(pk[2 * ks][1], srcB);
        u32 c0w = __shfl(pk[2 * ks + 1][0], srcA);
        u32 c1 = __shfl(pk[2 * ks + 1][1], srcA);
        u32 d0 = __shfl(pk[2 * ks + 1][0], srcB);
        u32 d1 = __shfl(pk[2 * ks + 1][1], srcB);
        union { u32 w[4]; short8 s8; } pu;
        pu.w[0] = (hi < 2) ? a0 : c0w;
        pu.w[1] = (hi < 2) ? a1 : c1;
        pu.w[2] = (hi < 2) ? b0 : d0;
        pu.w[3] = (hi < 2) ? b1 : d1;
        short8 pf = pu.s8;
#pragma unroll
        for (int dn = 0; dn < 4; ++dn) {
            short8 vf = *(const short8*)&Vsb[(dn * 16 + fr) * 72 + ks * 32 + fk];
            o[dn] = mfma16(vf, pf, o[dn]);
        }
    }
}

// ---------------- causal GQA flash attention, paired q-tiles for load balance ----------
__global__ __launch_bounds__(256) void attn_kernel(
    const u16* __restrict__ q, const u16* __restrict__ k, const u16* __restrict__ vt,
    u16* __restrict__ ctx) {
    __shared__ u16 Ks[2][64 * 72];
    __shared__ u16 Vs[2][64 * 72];
    const int jp = blockIdx.x, h = blockIdx.y, b = blockIdx.z;
    const int qtA = jp, qtB = 15 - jp;
    const int g = h >> 2;
    const int tid = threadIdx.x, wid = tid >> 6, lane = tid & 63;
    const int fr = lane & 15, hi = lane >> 4, fk = hi * 8;
    const int sqA = qtA * 64 + wid * 16 + fr;
    const int sqB = qtB * 64 + wid * 16 + fr;
    short8 qfA[2], qfB[2];
    {
        const u16* qp = &q[((size_t)(b * 1024 + sqA)) * 2048 + h * 64];
        qfA[0] = *(const short8*)&qp[fk];
        qfA[1] = *(const short8*)&qp[32 + fk];
        const u16* qp2 = &q[((size_t)(b * 1024 + sqB)) * 2048 + h * 64];
        qfB[0] = *(const short8*)&qp2[fk];
        qfB[1] = *(const short8*)&qp2[32 + fk];
    }
    f32x4 oA[4] = {}, oB[4] = {};
    float mA = -3.0e38f, lA = 0.0f, mB = -3.0e38f, lB = 0.0f;
    const int r0 = tid >> 3, c0 = (tid & 7) * 8;
    const u16* kbase = k + ((size_t)b * 1024) * 512 + g * 64;
    const u16* vbase = vt + ((size_t)(g * 64)) * 4096 + b * 1024;
    const int srcA = fr | ((2 * (hi & 1)) << 4);
    const int srcB = srcA + 16;

    auto stage_load = [&](int kt, short8& k0, short8& k1, short8& v0, short8& v1) {
        const u16* kg = kbase + (size_t)(kt * 64) * 512;
        const u16* vg = vbase + kt * 64;
        k0 = *(const short8*)&kg[(size_t)r0 * 512 + c0];
        k1 = *(const short8*)&kg[(size_t)(r0 + 32) * 512 + c0];
        v0 = *(const short8*)&vg[(size_t)r0 * 4096 + c0];
        v1 = *(const short8*)&vg[(size_t)(r0 + 32) * 4096 + c0];
    };
    auto stage_write = [&](int buf, short8 k0, short8 k1, short8 v0, short8 v1) {
        *(short8*)&Ks[buf][r0 * 72 + c0] = k0;
        *(short8*)&Ks[buf][(r0 + 32) * 72 + c0] = k1;
        *(short8*)&Vs[buf][r0 * 72 + c0] = v0;
        *(short8*)&Vs[buf][(r0 + 32) * 72 + c0] = v1;
    };

    {
        short8 a, bb, c, d;
        stage_load(0, a, bb, c, d);
        stage_write(0, a, bb, c, d);
    }
    __syncthreads();

    for (int kt = 0; kt <= qtB; ++kt) {
        const int cur = kt & 1;
        const bool more = (kt < qtB);
        short8 nk0, nk1, nv0, nv1;
        if (more) stage_load(kt + 1, nk0, nk1, nv0, nv1);

        if (kt < qtA)
            attn_tile_step<false>(Ks[cur], Vs[cur], qfA, oA, mA, lA, sqA, kt, wid, fr, hi, fk, srcA, srcB);
        else if (kt == qtA)
            attn_tile_step<true>(Ks[cur], Vs[cur], qfA, oA, mA, lA, sqA, kt, wid, fr, hi, fk, srcA, srcB);
        if (kt < qtB)
            attn_tile_step<false>(Ks[cur], Vs[cur], qfB, oB, mB, lB, sqB, kt, wid, fr, hi, fk, srcA, srcB);
        else
            attn_tile_step<true>(Ks[cur], Vs[cur], qfB, oB, mB, lB, sqB, kt, wid, fr, hi, fk, srcA, srcB);

        if (more) {
            stage_write(cur ^ 1, nk0, nk1, nv0, nv1);
            __syncthreads();
        }
    }
    {
        const float linv = 1.0f / lA;
        const size_t obase = ((size_t)(b * 1024 + sqA)) * 2048 + h * 64;
#pragma unroll
        for (int dn = 0; dn < 4; ++dn) {
            u16x4 w;
#pragma unroll
            for (int j = 0; j < 4; ++j) w[j] = f2bf(oA[dn][j] * linv);
            *(u16x4*)&ctx[obase + dn * 16 + hi * 4] = w;
        }
    }
    {
        const float linv = 1.0f / lB;
        const size_t obase = ((size_t)(b * 1024 + sqB)) * 2048 + h * 64;
#pragma unroll
        for (int dn = 0; dn < 4; ++dn) {
            u16x4 w;
#pragma unroll
            for (int j = 0; j < 4; ++j) w[j] = f2bf(oB[dn][j] * linv);
            *(u16x4*)&ctx[obase + dn * 16 + hi * 4] = w;
        }
    }
}

extern "C" void kernel_launch(void* const* d_in, const int* in_sizes, int n_in,
                              void* d_out, int out_size, void* d_ws, size_t ws_size,
                              hipStream_t stream) {
    const float* x    = (const float*)d_in[0];
    const float* fcos = (const float*)d_in[1];
    const float* fsin = (const float*)d_in[2];
    const float* Wq   = (const float*)d_in[3];
    const float* Wk   = (const float*)d_in[4];
    const float* Wv   = (const float*)d_in[5];
    const float* Wo   = (const float*)d_in[6];
    const float* qA   = (const float*)d_in[7];
    const float* qB   = (const float*)d_in[8];
    const float* kA   = (const float*)d_in[9];
    const float* kB   = (const float*)d_in[10];
    const float* vA   = (const float*)d_in[11];
    const float* vB   = (const float*)d_in[12];
    float* out = (float*)d_out;

    char* ws = (char*)d_ws;
    size_t off = 0;
    auto alloc = [&](size_t bytes) { char* p = ws + off; off += (bytes + 255) & ~(size_t)255; return p; };
    u16* xb   = (u16*)alloc(4096 * 2048 * 2);
    u16* WqT  = (u16*)alloc(2048 * 2048 * 2);
    u16* WkT  = (u16*)alloc(512 * 2048 * 2);
    u16* WvT  = (u16*)alloc(512 * 2048 * 2);
    u16* WoT  = (u16*)alloc(2048 * 2048 * 2);
    u16* qbuf = (u16*)alloc(4096 * 2048 * 2);
    u16* kbuf = (u16*)alloc(4096 * 512 * 2);
    u16* VT2  = (u16*)alloc(512 * 4096 * 2);   // V^T: [(g*64+d)][b*1024+s]
    u16* ctx  = (u16*)alloc(4096 * 2048 * 2);

    cast_x_kernel<<<2048, 256, 0, stream>>>(x, xb, 4096 * 2048);

    dim3 tb(32, 32);
    // W_eff = W + 2*A@B folded during transpose-cast (kills the skinny LoRA-A GEMM)
    fused_wT_kernel<<<dim3(64, 64), tb, 0, stream>>>(Wq, qA, qB, WqT, 2048, 2048);
    fused_wT_kernel<<<dim3(16, 64), tb, 0, stream>>>(Wk, kA, kB, WkT, 2048, 512);
    fused_wT_kernel<<<dim3(16, 64), tb, 0, stream>>>(Wv, vA, vB, WvT, 2048, 512);
    transpose_cast_kernel<<<dim3(64, 64), tb, 0, stream>>>(Wo, WoT, 2048, 2048);

    gemm_kernel<0><<<dim3(32, 16), 256, 0, stream>>>(xb, WqT, qbuf, 2048);
    gemm_kernel<0><<<dim3(32, 4), 256, 0, stream>>>(xb, WkT, kbuf, 512);
    // V computed TRANSPOSED: VT2[feat][b*1024+s] = (x@Wv_eff)^T via operand swap
    gemm_kernel<0><<<dim3(4, 32), 256, 0, stream>>>(WvT, xb, VT2, 4096);

    rope_kernel<<<4096, 256, 0, stream>>>(qbuf, fcos, fsin, 2048, 11);
    rope_kernel<<<1024, 256, 0, stream>>>(kbuf, fcos, fsin, 512, 9);

    attn_kernel<<<dim3(8, 32, 4), 256, 0, stream>>>(qbuf, kbuf, VT2, ctx);

    gemm_kernel<1><<<dim3(32, 16), 256, 0, stream>>>(ctx, WoT, out, 2048);
}

// Round 6
// 298.489 us; speedup vs baseline: 1.7625x; 1.0248x over previous
//
#include <hip/hip_runtime.h>

typedef unsigned short u16;
typedef unsigned int u32;
typedef __attribute__((ext_vector_type(8))) short short8;
typedef __attribute__((ext_vector_type(4))) float f32x4;
typedef __attribute__((ext_vector_type(4))) u16 u16x4;

#define LOG2E 1.4426950408889634f
#define SCL2 (0.125f * LOG2E)

static __device__ __forceinline__ float bf2f(u16 u) {
    return __uint_as_float(((unsigned)u) << 16);
}
static __device__ __forceinline__ u16 f2bf(float f) {
    unsigned u = __float_as_uint(f);
    unsigned r = (u + 0x7FFF + ((u >> 16) & 1)) >> 16;
    return (u16)r;
}
static __device__ __forceinline__ u32 cvtpk(float lo, float hi) {
    u32 r;
    asm("v_cvt_pk_bf16_f32 %0, %1, %2" : "=v"(r) : "v"(lo), "v"(hi));
    return r;
}
static __device__ __forceinline__ f32x4 mfma16(short8 a, short8 b, f32x4 c) {
    return __builtin_amdgcn_mfma_f32_16x16x32_bf16(a, b, c, 0, 0, 0);
}
static __device__ __forceinline__ void gload_lds16(const void* g, void* l) {
    __builtin_amdgcn_global_load_lds(
        (const __attribute__((address_space(1))) void*)g,
        (__attribute__((address_space(3))) void*)l, 16, 0, 0);
}

// ---------------- cast x (fp32 -> bf16), vectorized ----------------
__global__ void cast_x_kernel(const float* __restrict__ x, u16* __restrict__ xb, int n) {
    int i = (blockIdx.x * blockDim.x + threadIdx.x) * 4;
    int stride = gridDim.x * blockDim.x * 4;
    for (; i < n; i += stride) {
        f32x4 v = *(const f32x4*)&x[i];
        u16x4 o;
        o.x = f2bf(v.x); o.y = f2bf(v.y); o.z = f2bf(v.z); o.w = f2bf(v.w);
        *(u16x4*)&xb[i] = o;
    }
}

// ---------------- transpose + cast: src[R][C] fp32 -> dst[C][R] bf16 ----------------
__global__ void transpose_cast_kernel(const float* __restrict__ src, u16* __restrict__ dst,
                                      int R, int C) {
    __shared__ float tile[32][33];
    int c0 = blockIdx.x * 32, r0 = blockIdx.y * 32;
    int tx = threadIdx.x, ty = threadIdx.y;
    tile[ty][tx] = src[(size_t)(r0 + ty) * C + c0 + tx];
    __syncthreads();
    dst[(size_t)(c0 + ty) * R + r0 + tx] = f2bf(tile[tx][ty]);
}

// ---------------- fused LoRA weight fold + transpose + cast ----------------
// dst[C][R] bf16 = (W[R][C] + 2 * A[R][16] @ Bm[16][C])^T
__global__ void fused_wT_kernel(const float* __restrict__ W, const float* __restrict__ A,
                                const float* __restrict__ Bm, u16* __restrict__ dst,
                                int R, int C) {
    __shared__ float tile[32][33];
    __shared__ float As[32][17];
    __shared__ float Bs[16][33];
    int c0 = blockIdx.x * 32, r0 = blockIdx.y * 32;
    int tx = threadIdx.x, ty = threadIdx.y;
    tile[ty][tx] = W[(size_t)(r0 + ty) * C + c0 + tx];
    if (tx < 16) As[ty][tx] = A[(r0 + ty) * 16 + tx];
    if (ty < 16) Bs[ty][tx] = Bm[(size_t)ty * C + c0 + tx];
    __syncthreads();
    float acc = 0.0f;
#pragma unroll
    for (int rr = 0; rr < 16; ++rr) acc += As[tx][rr] * Bs[rr][ty];
    dst[(size_t)(c0 + ty) * R + r0 + tx] = f2bf(tile[tx][ty] + 2.0f * acc);
}

// ---------------- GEMM (m97 recipe + XCD swizzle) ----------------
// C[M][*] = A[M][2048] @ Bt[Nn][2048]^T
// MODE 0: bf16 out (stride Nn); MODE 1: f32 out; MODE 2: QK split (q stride 2048 / k stride 512)
template <int MODE>
__global__ __launch_bounds__(256) void gemm_kernel(
    const u16* __restrict__ A, const u16* __restrict__ Bt, void* __restrict__ Cout,
    void* __restrict__ Cout2, int Nn) {
    constexpr int K = 2048;
    __shared__ u16 As[128 * 64];
    __shared__ u16 Bs[128 * 64];
    const int tid = threadIdx.x;
    const int wid = tid >> 6, lane = tid & 63;
    const int nwg = gridDim.x * gridDim.y;
    int flat = blockIdx.y * gridDim.x + blockIdx.x;
    flat = (flat & 7) * (nwg >> 3) + (flat >> 3);
    const int mbase = (flat % gridDim.x) * 128;
    const int nbase = (flat / gridDim.x) * 128;
    const int wrow = (wid >> 1) * 64, wcol = (wid & 1) * 64;
    const int fr = lane & 15, fk = (lane >> 4) * 8;
    const int l8 = lane >> 3, c8 = (lane & 7) * 8;
    f32x4 acc[4][4] = {};
    const u16* Ag = A + (size_t)mbase * K;
    const u16* Bg = Bt + (size_t)nbase * K;
    for (int kt = 0; kt < K; kt += 64) {
        __syncthreads();
#pragma unroll
        for (int i = 0; i < 4; ++i) {
            const int r8 = (i * 4 + wid) * 8;
            gload_lds16(&Ag[(size_t)(r8 + l8) * K + kt + c8], &As[r8 * 64]);
            gload_lds16(&Bg[(size_t)(r8 + l8) * K + kt + c8], &Bs[r8 * 64]);
        }
        __syncthreads();
#pragma unroll
        for (int ks = 0; ks < 2; ++ks) {
            short8 af[4], bfr[4];
#pragma unroll
            for (int i = 0; i < 4; ++i) {
                af[i]  = *(const short8*)&As[(wrow + i * 16 + fr) * 64 + ks * 32 + fk];
                bfr[i] = *(const short8*)&Bs[(wcol + i * 16 + fr) * 64 + ks * 32 + fk];
            }
#pragma unroll
            for (int mi = 0; mi < 4; ++mi)
#pragma unroll
                for (int ni = 0; ni < 4; ++ni)
                    acc[mi][ni] = mfma16(af[mi], bfr[ni], acc[mi][ni]);
        }
    }
    const int rb = mbase + wrow + ((lane >> 4) << 2);
    const int cb = nbase + wcol + fr;
    if (MODE == 1) {
        float* C = (float*)Cout;
#pragma unroll
        for (int mi = 0; mi < 4; ++mi)
#pragma unroll
            for (int j = 0; j < 4; ++j) {
                const size_t ro = (size_t)(rb + mi * 16 + j) * Nn;
#pragma unroll
                for (int ni = 0; ni < 4; ++ni) C[ro + cb + ni * 16] = acc[mi][ni][j];
            }
    } else {
        u16* C;
        int cstride, cc;
        if (MODE == 2 && nbase >= 2048) {
            C = (u16*)Cout2; cstride = 512; cc = cb - 2048;
        } else {
            C = (u16*)Cout; cstride = (MODE == 2) ? 2048 : Nn; cc = cb;
        }
#pragma unroll
        for (int mi = 0; mi < 4; ++mi)
#pragma unroll
            for (int j = 0; j < 4; ++j) {
                const size_t ro = (size_t)(rb + mi * 16 + j) * cstride;
#pragma unroll
                for (int ni = 0; ni < 4; ++ni) C[ro + cc + ni * 16] = f2bf(acc[mi][ni][j]);
            }
    }
}

// ---------------- RoPE in place on bf16 [4096][width], optional pre-scale ----------------
__global__ void rope_kernel(u16* __restrict__ t, const float* __restrict__ cosb,
                            const float* __restrict__ sinb, int width, int shift, float scale) {
    int idx = blockIdx.x * blockDim.x + threadIdx.x;
    int base = idx * 8;
    int row = base >> shift;
    int within = base & (width - 1);
    int d0 = within & 63;
    int i0 = d0 >> 1;
    int s = row & 1023;
    short8 v = *(short8*)&t[base];
    f32x4 cv = *(const f32x4*)&cosb[s * 32 + i0];
    f32x4 sv = *(const f32x4*)&sinb[s * 32 + i0];
#pragma unroll
    for (int p = 0; p < 4; ++p) {
        float c = cv[p] * scale, sn = sv[p] * scale;
        float x0 = bf2f((u16)v[2 * p]);
        float x1 = bf2f((u16)v[2 * p + 1]);
        float r0 = x0 * c - x1 * sn;
        float r1 = x0 * sn + x1 * c;
        v[2 * p] = (short)f2bf(r0);
        v[2 * p + 1] = (short)f2bf(r1);
    }
    *(short8*)&t[base] = v;
}

// ---------------- attention tile step ----------------
// LDS layout: linear [64][64] with 16B-slice swizzle slice_lds = slice_g ^ (row&7).
// Q pre-scaled by SCL2 in rope. P reshape via permlane32/16_swap (T12).
template <bool DIAG>
static __device__ __forceinline__ void attn_tile_step(
    const u16* __restrict__ Ksb, const u16* __restrict__ Vsb,
    const short8* qf, f32x4* o, float& m, float& l,
    int sq, int kvb, int wid, int fr, int hi) {
    f32x4 s[4];
    const int sw = fr & 7;
#pragma unroll
    for (int mi = 0; mi < 4; ++mi) {
        if (!DIAG || mi <= wid) {
            const int row = (mi * 16 + fr) * 64;
            short8 kf0 = *(const short8*)&Ksb[row + ((hi ^ sw) * 8)];
            short8 kf1 = *(const short8*)&Ksb[row + (((4 + hi) ^ sw) * 8)];
            f32x4 z = {};
            z = mfma16(kf0, qf[0], z);
            z = mfma16(kf1, qf[1], z);
#pragma unroll
            for (int j = 0; j < 4; ++j) {
                float val = z[j];
                if (DIAG && mi == wid && (kvb + mi * 16 + hi * 4 + j > sq)) val = -3.0e38f;
                s[mi][j] = val;
            }
        } else {
            s[mi][0] = -3.0e38f; s[mi][1] = -3.0e38f;
            s[mi][2] = -3.0e38f; s[mi][3] = -3.0e38f;
        }
    }
    float pmax = fmaxf(fmaxf(fmaxf(s[0][0], s[0][1]), fmaxf(s[0][2], s[0][3])),
                       fmaxf(fmaxf(s[1][0], s[1][1]), fmaxf(s[1][2], s[1][3])));
    pmax = fmaxf(pmax, fmaxf(fmaxf(fmaxf(s[2][0], s[2][1]), fmaxf(s[2][2], s[2][3])),
                             fmaxf(fmaxf(s[3][0], s[3][1]), fmaxf(s[3][2], s[3][3]))));
    pmax = fmaxf(pmax, __shfl_xor(pmax, 16));
    pmax = fmaxf(pmax, __shfl_xor(pmax, 32));
    if (__any(pmax > m + 8.0f)) {
        const float mnew = fmaxf(m, pmax);
        const float fsc = exp2f(m - mnew);
        l *= fsc;
        m = mnew;
#pragma unroll
        for (int dn = 0; dn < 4; ++dn)
#pragma unroll
            for (int j = 0; j < 4; ++j) o[dn][j] *= fsc;
    }
    float rs = 0.0f;
    u32 pk[4][2];
#pragma unroll
    for (int mi = 0; mi < 4; ++mi) {
        float p0 = exp2f(s[mi][0] - m);
        float p1 = exp2f(s[mi][1] - m);
        float p2 = exp2f(s[mi][2] - m);
        float p3 = exp2f(s[mi][3] - m);
        rs += (p0 + p1) + (p2 + p3);
        pk[mi][0] = cvtpk(p0, p1);
        pk[mi][1] = cvtpk(p2, p3);
    }
    rs += __shfl_xor(rs, 16);
    rs += __shfl_xor(rs, 32);
    l += rs;
    const int ksmax = DIAG ? (wid >> 1) : 1;
#pragma unroll
    for (int ks = 0; ks < 2; ++ks) {
        if (ks > ksmax) continue;
        // B-fragment build: (w0,w2) = swap16(swap32(pk[2ks][0], pk[2ks+1][0])); same for w1,w3
        u32 w0 = pk[2 * ks][0], w2 = pk[2 * ks + 1][0];
        u32 w1 = pk[2 * ks][1], w3 = pk[2 * ks + 1][1];
        asm volatile("v_permlane32_swap_b32 %0, %1" : "+v"(w0), "+v"(w2));
        asm volatile("v_permlane16_swap_b32 %0, %1" : "+v"(w0), "+v"(w2));
        asm volatile("v_permlane32_swap_b32 %0, %1" : "+v"(w1), "+v"(w3));
        asm volatile("v_permlane16_swap_b32 %0, %1" : "+v"(w1), "+v"(w3));
        union { u32 w[4]; short8 s8; } pu;
        pu.w[0] = w0; pu.w[1] = w1; pu.w[2] = w2; pu.w[3] = w3;
        short8 pf = pu.s8;
#pragma unroll
        for (int dn = 0; dn < 4; ++dn) {
            const int row = (dn * 16 + fr) * 64;
            short8 vf = *(const short8*)&Vsb[row + (((ks * 4 + hi) ^ sw) * 8)];
            o[dn] = mfma16(vf, pf, o[dn]);
        }
    }
}

// ---------------- causal GQA flash attention, paired q-tiles, DMA-staged K/V ----------
__global__ __launch_bounds__(256) void attn_kernel(
    const u16* __restrict__ q, const u16* __restrict__ k, const u16* __restrict__ vt,
    u16* __restrict__ ctx) {
    __shared__ u16 Ks[2][64 * 64];
    __shared__ u16 Vs[2][64 * 64];
    const int jp = blockIdx.x, h = blockIdx.y, b = blockIdx.z;
    const int qtA = jp, qtB = 15 - jp;
    const int g = h >> 2;
    const int tid = threadIdx.x, wid = tid >> 6, lane = tid & 63;
    const int fr = lane & 15, hi = lane >> 4, fk = hi * 8;
    const int sqA = qtA * 64 + wid * 16 + fr;
    const int sqB = qtB * 64 + wid * 16 + fr;
    short8 qfA[2], qfB[2];
    {
        const u16* qp = &q[((size_t)(b * 1024 + sqA)) * 2048 + h * 64];
        qfA[0] = *(const short8*)&qp[fk];
        qfA[1] = *(const short8*)&qp[32 + fk];
        const u16* qp2 = &q[((size_t)(b * 1024 + sqB)) * 2048 + h * 64];
        qfB[0] = *(const short8*)&qp2[fk];
        qfB[1] = *(const short8*)&qp2[32 + fk];
    }
    f32x4 oA[4] = {}, oB[4] = {};
    float mA = -3.0e38f, lA = 0.0f, mB = -3.0e38f, lB = 0.0f;
    const u16* kbase = k + ((size_t)b * 1024) * 512 + g * 64;
    const u16* vbase = vt + ((size_t)(g * 64)) * 4096 + b * 1024;
    const int l8 = lane >> 3;
    const int sw8 = ((lane & 7) ^ l8) * 8;   // pre-swizzled global 16B-slice

    auto stage = [&](int kt, int buf) {
        const u16* kg = kbase + (size_t)(kt * 64) * 512;
        const u16* vg = vbase + kt * 64;
#pragma unroll
        for (int i = 0; i < 2; ++i) {
            const int r8 = (i * 4 + wid) * 8;
            gload_lds16(&kg[(size_t)(r8 + l8) * 512 + sw8], &Ks[buf][r8 * 64]);
            gload_lds16(&vg[(size_t)(r8 + l8) * 4096 + sw8], &Vs[buf][r8 * 64]);
        }
    };

    stage(0, 0);
    for (int kt = 0; kt <= qtB; ++kt) {
        const int cur = kt & 1;
        __syncthreads();                       // publishes buf[cur] (drains DMA)
        if (kt < qtB) stage(kt + 1, cur ^ 1);  // async prefetch under compute
        const int kvb = kt * 64;
        if (kt < qtA)
            attn_tile_step<false>(Ks[cur], Vs[cur], qfA, oA, mA, lA, sqA, kvb, wid, fr, hi);
        else if (kt == qtA)
            attn_tile_step<true>(Ks[cur], Vs[cur], qfA, oA, mA, lA, sqA, kvb, wid, fr, hi);
        if (kt < qtB)
            attn_tile_step<false>(Ks[cur], Vs[cur], qfB, oB, mB, lB, sqB, kvb, wid, fr, hi);
        else
            attn_tile_step<true>(Ks[cur], Vs[cur], qfB, oB, mB, lB, sqB, kvb, wid, fr, hi);
    }
    {
        const float linv = 1.0f / lA;
        const size_t obase = ((size_t)(b * 1024 + sqA)) * 2048 + h * 64;
#pragma unroll
        for (int dn = 0; dn < 4; ++dn) {
            u16x4 w;
#pragma unroll
            for (int j = 0; j < 4; ++j) w[j] = f2bf(oA[dn][j] * linv);
            *(u16x4*)&ctx[obase + dn * 16 + hi * 4] = w;
        }
    }
    {
        const float linv = 1.0f / lB;
        const size_t obase = ((size_t)(b * 1024 + sqB)) * 2048 + h * 64;
#pragma unroll
        for (int dn = 0; dn < 4; ++dn) {
            u16x4 w;
#pragma unroll
            for (int j = 0; j < 4; ++j) w[j] = f2bf(oB[dn][j] * linv);
            *(u16x4*)&ctx[obase + dn * 16 + hi * 4] = w;
        }
    }
}

extern "C" void kernel_launch(void* const* d_in, const int* in_sizes, int n_in,
                              void* d_out, int out_size, void* d_ws, size_t ws_size,
                              hipStream_t stream) {
    const float* x    = (const float*)d_in[0];
    const float* fcos = (const float*)d_in[1];
    const float* fsin = (const float*)d_in[2];
    const float* Wq   = (const float*)d_in[3];
    const float* Wk   = (const float*)d_in[4];
    const float* Wv   = (const float*)d_in[5];
    const float* Wo   = (const float*)d_in[6];
    const float* qA   = (const float*)d_in[7];
    const float* qB   = (const float*)d_in[8];
    const float* kA   = (const float*)d_in[9];
    const float* kB   = (const float*)d_in[10];
    const float* vA   = (const float*)d_in[11];
    const float* vB   = (const float*)d_in[12];
    float* out = (float*)d_out;

    char* ws = (char*)d_ws;
    size_t off = 0;
    auto alloc = [&](size_t bytes) { char* p = ws + off; off += (bytes + 255) & ~(size_t)255; return p; };
    u16* xb    = (u16*)alloc((size_t)4096 * 2048 * 2);
    u16* WqkT  = (u16*)alloc((size_t)2560 * 2048 * 2);  // rows 0..2047 = Wq_eff^T, 2048..2559 = Wk_eff^T
    u16* WvT   = (u16*)alloc((size_t)512 * 2048 * 2);
    u16* WoT   = (u16*)alloc((size_t)2048 * 2048 * 2);
    u16* qbuf  = (u16*)alloc((size_t)4096 * 2048 * 2);
    u16* kbuf  = (u16*)alloc((size_t)4096 * 512 * 2);
    u16* VT2   = (u16*)alloc((size_t)512 * 4096 * 2);   // V^T: [(g*64+d)][b*1024+s]
    u16* ctx   = (u16*)alloc((size_t)4096 * 2048 * 2);

    cast_x_kernel<<<2048, 256, 0, stream>>>(x, xb, 4096 * 2048);

    dim3 tb(32, 32);
    fused_wT_kernel<<<dim3(64, 64), tb, 0, stream>>>(Wq, qA, qB, WqkT, 2048, 2048);
    fused_wT_kernel<<<dim3(16, 64), tb, 0, stream>>>(Wk, kA, kB, WqkT + (size_t)2048 * 2048, 2048, 512);
    fused_wT_kernel<<<dim3(16, 64), tb, 0, stream>>>(Wv, vA, vB, WvT, 2048, 512);
    transpose_cast_kernel<<<dim3(64, 64), tb, 0, stream>>>(Wo, WoT, 2048, 2048);

    // merged Q+K projection (Nn = 2560), epilogue splits into qbuf / kbuf
    gemm_kernel<2><<<dim3(32, 20), 256, 0, stream>>>(xb, WqkT, qbuf, kbuf, 2560);
    // V computed TRANSPOSED: VT2[feat][tok] = (x@Wv_eff)^T via operand swap
    gemm_kernel<0><<<dim3(4, 32), 256, 0, stream>>>(WvT, xb, VT2, nullptr, 4096);

    rope_kernel<<<4096, 256, 0, stream>>>(qbuf, fcos, fsin, 2048, 11, SCL2);  // q pre-scaled
    rope_kernel<<<1024, 256, 0, stream>>>(kbuf, fcos, fsin, 512, 9, 1.0f);

    attn_kernel<<<dim3(8, 32, 4), 256, 0, stream>>>(qbuf, kbuf, VT2, ctx);

    gemm_kernel<1><<<dim3(32, 16), 256, 0, stream>>>(ctx, WoT, out, nullptr, 2048);
}

// Round 7
// 261.030 us; speedup vs baseline: 2.0154x; 1.1435x over previous
//
#include <hip/hip_runtime.h>

typedef unsigned short u16;
typedef unsigned int u32;
typedef __attribute__((ext_vector_type(8))) short short8;
typedef __attribute__((ext_vector_type(4))) float f32x4;
typedef __attribute__((ext_vector_type(4))) u16 u16x4;

#define LOG2E 1.4426950408889634f
#define SCL2 (0.125f * LOG2E)

static __device__ __forceinline__ float bf2f(u16 u) {
    return __uint_as_float(((unsigned)u) << 16);
}
static __device__ __forceinline__ u16 f2bf(float f) {
    unsigned u = __float_as_uint(f);
    unsigned r = (u + 0x7FFF + ((u >> 16) & 1)) >> 16;
    return (u16)r;
}
static __device__ __forceinline__ u32 cvtpk(float lo, float hi) {
    u32 r;
    asm("v_cvt_pk_bf16_f32 %0, %1, %2" : "=v"(r) : "v"(lo), "v"(hi));
    return r;
}
static __device__ __forceinline__ f32x4 mfma16(short8 a, short8 b, f32x4 c) {
    return __builtin_amdgcn_mfma_f32_16x16x32_bf16(a, b, c, 0, 0, 0);
}
static __device__ __forceinline__ void gload_lds16(const void* g, void* l) {
    __builtin_amdgcn_global_load_lds(
        (const __attribute__((address_space(1))) void*)g,
        (__attribute__((address_space(3))) void*)l, 16, 0, 0);
}

// ---------------- cast x (fp32 -> bf16), vectorized ----------------
__global__ void cast_x_kernel(const float* __restrict__ x, u16* __restrict__ xb, int n) {
    int i = (blockIdx.x * blockDim.x + threadIdx.x) * 4;
    int stride = gridDim.x * blockDim.x * 4;
    for (; i < n; i += stride) {
        f32x4 v = *(const f32x4*)&x[i];
        u16x4 o;
        o.x = f2bf(v.x); o.y = f2bf(v.y); o.z = f2bf(v.z); o.w = f2bf(v.w);
        *(u16x4*)&xb[i] = o;
    }
}

// ---------------- transpose + cast: src[R][C] fp32 -> dst[C][R] bf16 ----------------
__global__ void transpose_cast_kernel(const float* __restrict__ src, u16* __restrict__ dst,
                                      int R, int C) {
    __shared__ float tile[32][33];
    int c0 = blockIdx.x * 32, r0 = blockIdx.y * 32;
    int tx = threadIdx.x, ty = threadIdx.y;
    tile[ty][tx] = src[(size_t)(r0 + ty) * C + c0 + tx];
    __syncthreads();
    dst[(size_t)(c0 + ty) * R + r0 + tx] = f2bf(tile[tx][ty]);
}

// ---------------- bf16 transpose: src[R][C] -> dst[C][R] ----------------
__global__ void transpose_bf16_kernel(const u16* __restrict__ src, u16* __restrict__ dst,
                                      int R, int C) {
    __shared__ u16 tile[32][33];
    int c0 = blockIdx.x * 32, r0 = blockIdx.y * 32;
    int tx = threadIdx.x, ty = threadIdx.y;
    tile[ty][tx] = src[(size_t)(r0 + ty) * C + c0 + tx];
    __syncthreads();
    dst[(size_t)(c0 + ty) * R + r0 + tx] = tile[tx][ty];
}

// ---------------- fused LoRA weight fold + transpose + cast ----------------
// dst[C][R] bf16 = (W[R][C] + 2 * A[R][16] @ Bm[16][C])^T
__global__ void fused_wT_kernel(const float* __restrict__ W, const float* __restrict__ A,
                                const float* __restrict__ Bm, u16* __restrict__ dst,
                                int R, int C) {
    __shared__ float tile[32][33];
    __shared__ float As[32][17];
    __shared__ float Bs[16][33];
    int c0 = blockIdx.x * 32, r0 = blockIdx.y * 32;
    int tx = threadIdx.x, ty = threadIdx.y;
    tile[ty][tx] = W[(size_t)(r0 + ty) * C + c0 + tx];
    if (tx < 16) As[ty][tx] = A[(r0 + ty) * 16 + tx];
    if (ty < 16) Bs[ty][tx] = Bm[(size_t)ty * C + c0 + tx];
    __syncthreads();
    float acc = 0.0f;
#pragma unroll
    for (int rr = 0; rr < 16; ++rr) acc += As[tx][rr] * Bs[rr][ty];
    dst[(size_t)(c0 + ty) * R + r0 + tx] = f2bf(tile[tx][ty] + 2.0f * acc);
}

// ---------------- GEMM: 128x128 tile, BK=64, double-buffered DMA + counted vmcnt ------
// C[M][*] = A[M][2048] @ Bt[Nn][2048]^T
// MODE 1: f32 out (stride Nn). MODE 2: QKV split (q 2048 / k 512 / v 512).
// XCD swizzle: each XCD owns an 8m x CN n rectangle (gx must be 32, gy must be 2*CN).
template <int MODE, int CN>
__global__ __launch_bounds__(256) void gemm_kernel(
    const u16* __restrict__ A, const u16* __restrict__ Bt, void* __restrict__ C0,
    void* __restrict__ C1, void* __restrict__ C2, int Nn) {
    constexpr int K = 2048;
    constexpr int NT = K / 64;
    __shared__ u16 As[2][128 * 64];
    __shared__ u16 Bs[2][128 * 64];
    const int tid = threadIdx.x;
    const int wid = tid >> 6, lane = tid & 63;
    // 2D-chunked XCD swizzle: xcd = dispatch round-robin id
    const int flat = blockIdx.y * gridDim.x + blockIdx.x;
    const int xcd = flat & 7, local = flat >> 3;
    const int mbase = (((xcd & 3) << 3) + (local & 7)) * 128;
    const int nbase = ((xcd >> 2) * CN + (local >> 3)) * 128;
    const int wrow = (wid >> 1) * 64, wcol = (wid & 1) * 64;
    const int fr = lane & 15, fk = (lane >> 4) * 8;
    const int l8 = lane >> 3, c8 = (lane & 7) * 8;
    f32x4 acc[4][4] = {};
    const u16* Ag = A + (size_t)mbase * K;
    const u16* Bg = Bt + (size_t)nbase * K;

    auto STAGE = [&](int kt, int buf) {
#pragma unroll
        for (int i = 0; i < 4; ++i) {
            const int r8 = (i * 4 + wid) * 8;
            gload_lds16(&Ag[(size_t)(r8 + l8) * K + kt * 64 + c8], &As[buf][r8 * 64]);
            gload_lds16(&Bg[(size_t)(r8 + l8) * K + kt * 64 + c8], &Bs[buf][r8 * 64]);
        }
    };

    STAGE(0, 0);
    for (int kt = 0; kt < NT; ++kt) {
        const int cur = kt & 1;
        if (kt < NT - 1) {
            STAGE(kt + 1, cur ^ 1);                       // prefetch stays in flight
            asm volatile("s_waitcnt vmcnt(8)" ::: "memory");   // only wait current tile
        } else {
            asm volatile("s_waitcnt vmcnt(0)" ::: "memory");
        }
        __builtin_amdgcn_s_barrier();                     // buf[cur] published
#pragma unroll
        for (int ks = 0; ks < 2; ++ks) {
            short8 af[4], bfr[4];
#pragma unroll
            for (int i = 0; i < 4; ++i) {
                af[i]  = *(const short8*)&As[cur][(wrow + i * 16 + fr) * 64 + ks * 32 + fk];
                bfr[i] = *(const short8*)&Bs[cur][(wcol + i * 16 + fr) * 64 + ks * 32 + fk];
            }
#pragma unroll
            for (int mi = 0; mi < 4; ++mi)
#pragma unroll
                for (int ni = 0; ni < 4; ++ni)
                    acc[mi][ni] = mfma16(af[mi], bfr[ni], acc[mi][ni]);
        }
        __builtin_amdgcn_s_barrier();                     // reads done before overwrite
    }
    const int rb = mbase + wrow + ((lane >> 4) << 2);
    const int cb = nbase + wcol + fr;
    if (MODE == 1) {
        float* C = (float*)C0;
#pragma unroll
        for (int mi = 0; mi < 4; ++mi)
#pragma unroll
            for (int j = 0; j < 4; ++j) {
                const size_t ro = (size_t)(rb + mi * 16 + j) * Nn;
#pragma unroll
                for (int ni = 0; ni < 4; ++ni) C[ro + cb + ni * 16] = acc[mi][ni][j];
            }
    } else {
        u16* C;
        int cstride, cc;
        if (nbase < 2048)      { C = (u16*)C0; cstride = 2048; cc = cb; }
        else if (nbase < 2560) { C = (u16*)C1; cstride = 512;  cc = cb - 2048; }
        else                   { C = (u16*)C2; cstride = 512;  cc = cb - 2560; }
#pragma unroll
        for (int mi = 0; mi < 4; ++mi)
#pragma unroll
            for (int j = 0; j < 4; ++j) {
                const size_t ro = (size_t)(rb + mi * 16 + j) * cstride;
#pragma unroll
                for (int ni = 0; ni < 4; ++ni) C[ro + cc + ni * 16] = f2bf(acc[mi][ni][j]);
            }
    }
}

// ---------------- RoPE in place on bf16 [4096][width], optional pre-scale ----------------
__global__ void rope_kernel(u16* __restrict__ t, const float* __restrict__ cosb,
                            const float* __restrict__ sinb, int width, int shift, float scale) {
    int idx = blockIdx.x * blockDim.x + threadIdx.x;
    int base = idx * 8;
    int row = base >> shift;
    int within = base & (width - 1);
    int d0 = within & 63;
    int i0 = d0 >> 1;
    int s = row & 1023;
    short8 v = *(short8*)&t[base];
    f32x4 cv = *(const f32x4*)&cosb[s * 32 + i0];
    f32x4 sv = *(const f32x4*)&sinb[s * 32 + i0];
#pragma unroll
    for (int p = 0; p < 4; ++p) {
        float c = cv[p] * scale, sn = sv[p] * scale;
        float x0 = bf2f((u16)v[2 * p]);
        float x1 = bf2f((u16)v[2 * p + 1]);
        float r0 = x0 * c - x1 * sn;
        float r1 = x0 * sn + x1 * c;
        v[2 * p] = (short)f2bf(r0);
        v[2 * p + 1] = (short)f2bf(r1);
    }
    *(short8*)&t[base] = v;
}

// ---------------- attention tile step ----------------
// LDS layout: linear [64][64] with 16B-slice swizzle slice_lds = slice_g ^ (row&7).
// Q pre-scaled by SCL2 in rope. P reshape via permlane32/16_swap (T12).
template <bool DIAG>
static __device__ __forceinline__ void attn_tile_step(
    const u16* __restrict__ Ksb, const u16* __restrict__ Vsb,
    const short8* qf, f32x4* o, float& m, float& l,
    int sq, int kvb, int wid, int fr, int hi) {
    f32x4 s[4];
    const int sw = fr & 7;
#pragma unroll
    for (int mi = 0; mi < 4; ++mi) {
        if (!DIAG || mi <= wid) {
            const int row = (mi * 16 + fr) * 64;
            short8 kf0 = *(const short8*)&Ksb[row + ((hi ^ sw) * 8)];
            short8 kf1 = *(const short8*)&Ksb[row + (((4 + hi) ^ sw) * 8)];
            f32x4 z = {};
            z = mfma16(kf0, qf[0], z);
            z = mfma16(kf1, qf[1], z);
#pragma unroll
            for (int j = 0; j < 4; ++j) {
                float val = z[j];
                if (DIAG && mi == wid && (kvb + mi * 16 + hi * 4 + j > sq)) val = -3.0e38f;
                s[mi][j] = val;
            }
        } else {
            s[mi][0] = -3.0e38f; s[mi][1] = -3.0e38f;
            s[mi][2] = -3.0e38f; s[mi][3] = -3.0e38f;
        }
    }
    float pmax = fmaxf(fmaxf(fmaxf(s[0][0], s[0][1]), fmaxf(s[0][2], s[0][3])),
                       fmaxf(fmaxf(s[1][0], s[1][1]), fmaxf(s[1][2], s[1][3])));
    pmax = fmaxf(pmax, fmaxf(fmaxf(fmaxf(s[2][0], s[2][1]), fmaxf(s[2][2], s[2][3])),
                             fmaxf(fmaxf(s[3][0], s[3][1]), fmaxf(s[3][2], s[3][3]))));
    pmax = fmaxf(pmax, __shfl_xor(pmax, 16));
    pmax = fmaxf(pmax, __shfl_xor(pmax, 32));
    if (__any(pmax > m + 8.0f)) {
        const float mnew = fmaxf(m, pmax);
        const float fsc = exp2f(m - mnew);
        l *= fsc;
        m = mnew;
#pragma unroll
        for (int dn = 0; dn < 4; ++dn)
#pragma unroll
            for (int j = 0; j < 4; ++j) o[dn][j] *= fsc;
    }
    float rs = 0.0f;
    u32 pk[4][2];
#pragma unroll
    for (int mi = 0; mi < 4; ++mi) {
        float p0 = exp2f(s[mi][0] - m);
        float p1 = exp2f(s[mi][1] - m);
        float p2 = exp2f(s[mi][2] - m);
        float p3 = exp2f(s[mi][3] - m);
        rs += (p0 + p1) + (p2 + p3);
        pk[mi][0] = cvtpk(p0, p1);
        pk[mi][1] = cvtpk(p2, p3);
    }
    rs += __shfl_xor(rs, 16);
    rs += __shfl_xor(rs, 32);
    l += rs;
    const int ksmax = DIAG ? (wid >> 1) : 1;
#pragma unroll
    for (int ks = 0; ks < 2; ++ks) {
        if (ks > ksmax) continue;
        u32 w0 = pk[2 * ks][0], w2 = pk[2 * ks + 1][0];
        u32 w1 = pk[2 * ks][1], w3 = pk[2 * ks + 1][1];
        asm volatile("v_permlane32_swap_b32 %0, %1" : "+v"(w0), "+v"(w2));
        asm volatile("v_permlane16_swap_b32 %0, %1" : "+v"(w0), "+v"(w2));
        asm volatile("v_permlane32_swap_b32 %0, %1" : "+v"(w1), "+v"(w3));
        asm volatile("v_permlane16_swap_b32 %0, %1" : "+v"(w1), "+v"(w3));
        union { u32 w[4]; short8 s8; } pu;
        pu.w[0] = w0; pu.w[1] = w1; pu.w[2] = w2; pu.w[3] = w3;
        short8 pf = pu.s8;
#pragma unroll
        for (int dn = 0; dn < 4; ++dn) {
            const int row = (dn * 16 + fr) * 64;
            short8 vf = *(const short8*)&Vsb[row + (((ks * 4 + hi) ^ sw) * 8)];
            o[dn] = mfma16(vf, pf, o[dn]);
        }
    }
}

// ---------------- causal GQA flash attention, paired q-tiles, DMA-staged K/V ----------
__global__ __launch_bounds__(256) void attn_kernel(
    const u16* __restrict__ q, const u16* __restrict__ k, const u16* __restrict__ vt,
    u16* __restrict__ ctx) {
    __shared__ u16 Ks[2][64 * 64];
    __shared__ u16 Vs[2][64 * 64];
    const int jp = blockIdx.x, h = blockIdx.y, b = blockIdx.z;
    const int qtA = jp, qtB = 15 - jp;
    const int g = h >> 2;
    const int tid = threadIdx.x, wid = tid >> 6, lane = tid & 63;
    const int fr = lane & 15, hi = lane >> 4, fk = hi * 8;
    const int sqA = qtA * 64 + wid * 16 + fr;
    const int sqB = qtB * 64 + wid * 16 + fr;
    short8 qfA[2], qfB[2];
    {
        const u16* qp = &q[((size_t)(b * 1024 + sqA)) * 2048 + h * 64];
        qfA[0] = *(const short8*)&qp[fk];
        qfA[1] = *(const short8*)&qp[32 + fk];
        const u16* qp2 = &q[((size_t)(b * 1024 + sqB)) * 2048 + h * 64];
        qfB[0] = *(const short8*)&qp2[fk];
        qfB[1] = *(const short8*)&qp2[32 + fk];
    }
    f32x4 oA[4] = {}, oB[4] = {};
    float mA = -3.0e38f, lA = 0.0f, mB = -3.0e38f, lB = 0.0f;
    const u16* kbase = k + ((size_t)b * 1024) * 512 + g * 64;
    const u16* vbase = vt + ((size_t)(g * 64)) * 4096 + b * 1024;
    const int l8 = lane >> 3;
    const int sw8 = ((lane & 7) ^ l8) * 8;   // pre-swizzled global 16B-slice

    auto stage = [&](int kt, int buf) {
        const u16* kg = kbase + (size_t)(kt * 64) * 512;
        const u16* vg = vbase + kt * 64;
#pragma unroll
        for (int i = 0; i < 2; ++i) {
            const int r8 = (i * 4 + wid) * 8;
            gload_lds16(&kg[(size_t)(r8 + l8) * 512 + sw8], &Ks[buf][r8 * 64]);
            gload_lds16(&vg[(size_t)(r8 + l8) * 4096 + sw8], &Vs[buf][r8 * 64]);
        }
    };

    stage(0, 0);
    for (int kt = 0; kt <= qtB; ++kt) {
        const int cur = kt & 1;
        __syncthreads();                       // publishes buf[cur] (drains DMA)
        if (kt < qtB) stage(kt + 1, cur ^ 1);  // async prefetch under compute
        const int kvb = kt * 64;
        if (kt < qtA)
            attn_tile_step<false>(Ks[cur], Vs[cur], qfA, oA, mA, lA, sqA, kvb, wid, fr, hi);
        else if (kt == qtA)
            attn_tile_step<true>(Ks[cur], Vs[cur], qfA, oA, mA, lA, sqA, kvb, wid, fr, hi);
        if (kt < qtB)
            attn_tile_step<false>(Ks[cur], Vs[cur], qfB, oB, mB, lB, sqB, kvb, wid, fr, hi);
        else
            attn_tile_step<true>(Ks[cur], Vs[cur], qfB, oB, mB, lB, sqB, kvb, wid, fr, hi);
    }
    {
        const float linv = 1.0f / lA;
        const size_t obase = ((size_t)(b * 1024 + sqA)) * 2048 + h * 64;
#pragma unroll
        for (int dn = 0; dn < 4; ++dn) {
            u16x4 w;
#pragma unroll
            for (int j = 0; j < 4; ++j) w[j] = f2bf(oA[dn][j] * linv);
            *(u16x4*)&ctx[obase + dn * 16 + hi * 4] = w;
        }
    }
    {
        const float linv = 1.0f / lB;
        const size_t obase = ((size_t)(b * 1024 + sqB)) * 2048 + h * 64;
#pragma unroll
        for (int dn = 0; dn < 4; ++dn) {
            u16x4 w;
#pragma unroll
            for (int j = 0; j < 4; ++j) w[j] = f2bf(oB[dn][j] * linv);
            *(u16x4*)&ctx[obase + dn * 16 + hi * 4] = w;
        }
    }
}

extern "C" void kernel_launch(void* const* d_in, const int* in_sizes, int n_in,
                              void* d_out, int out_size, void* d_ws, size_t ws_size,
                              hipStream_t stream) {
    const float* x    = (const float*)d_in[0];
    const float* fcos = (const float*)d_in[1];
    const float* fsin = (const float*)d_in[2];
    const float* Wq   = (const float*)d_in[3];
    const float* Wk   = (const float*)d_in[4];
    const float* Wv   = (const float*)d_in[5];
    const float* Wo   = (const float*)d_in[6];
    const float* qA   = (const float*)d_in[7];
    const float* qB   = (const float*)d_in[8];
    const float* kA   = (const float*)d_in[9];
    const float* kB   = (const float*)d_in[10];
    const float* vA   = (const float*)d_in[11];
    const float* vB   = (const float*)d_in[12];
    float* out = (float*)d_out;

    char* ws = (char*)d_ws;
    size_t off = 0;
    auto alloc = [&](size_t bytes) { char* p = ws + off; off += (bytes + 255) & ~(size_t)255; return p; };
    u16* xb     = (u16*)alloc((size_t)4096 * 2048 * 2);
    u16* WqkvT  = (u16*)alloc((size_t)3072 * 2048 * 2);  // rows: 0..2047 q, 2048..2559 k, 2560..3071 v
    u16* WoT    = (u16*)alloc((size_t)2048 * 2048 * 2);
    u16* qbuf   = (u16*)alloc((size_t)4096 * 2048 * 2);
    u16* kbuf   = (u16*)alloc((size_t)4096 * 512 * 2);
    u16* vbuf   = (u16*)alloc((size_t)4096 * 512 * 2);
    u16* VT2    = (u16*)alloc((size_t)512 * 4096 * 2);   // V^T: [(g*64+d)][b*1024+s]
    u16* ctx    = (u16*)alloc((size_t)4096 * 2048 * 2);

    cast_x_kernel<<<2048, 256, 0, stream>>>(x, xb, 4096 * 2048);

    dim3 tb(32, 32);
    fused_wT_kernel<<<dim3(64, 64), tb, 0, stream>>>(Wq, qA, qB, WqkvT, 2048, 2048);
    fused_wT_kernel<<<dim3(16, 64), tb, 0, stream>>>(Wk, kA, kB, WqkvT + (size_t)2048 * 2048, 2048, 512);
    fused_wT_kernel<<<dim3(16, 64), tb, 0, stream>>>(Wv, vA, vB, WqkvT + (size_t)2560 * 2048, 2048, 512);
    transpose_cast_kernel<<<dim3(64, 64), tb, 0, stream>>>(Wo, WoT, 2048, 2048);

    // merged QKV projection: N = 3072, grid 32x24 = 768 blocks (3/CU)
    gemm_kernel<2, 12><<<dim3(32, 24), 256, 0, stream>>>(xb, WqkvT, qbuf, kbuf, vbuf, 3072);
    // V^T for attention
    transpose_bf16_kernel<<<dim3(16, 128), tb, 0, stream>>>(vbuf, VT2, 4096, 512);

    rope_kernel<<<4096, 256, 0, stream>>>(qbuf, fcos, fsin, 2048, 11, SCL2);  // q pre-scaled
    rope_kernel<<<1024, 256, 0, stream>>>(kbuf, fcos, fsin, 512, 9, 1.0f);

    attn_kernel<<<dim3(8, 32, 4), 256, 0, stream>>>(qbuf, kbuf, VT2, ctx);

    gemm_kernel<1, 8><<<dim3(32, 16), 256, 0, stream>>>(ctx, WoT, out, nullptr, nullptr, 2048);
}

// Round 8
// 225.593 us; speedup vs baseline: 2.3320x; 1.1571x over previous
//
#include <hip/hip_runtime.h>

typedef unsigned short u16;
typedef unsigned int u32;
typedef __attribute__((ext_vector_type(8))) short short8;
typedef __attribute__((ext_vector_type(4))) float f32x4;
typedef __attribute__((ext_vector_type(4))) u16 u16x4;

#define LOG2E 1.4426950408889634f
#define SCL2 (0.125f * LOG2E)

static __device__ __forceinline__ float bf2f(u16 u) {
    return __uint_as_float(((unsigned)u) << 16);
}
static __device__ __forceinline__ u16 f2bf(float f) {
    unsigned u = __float_as_uint(f);
    unsigned r = (u + 0x7FFF + ((u >> 16) & 1)) >> 16;
    return (u16)r;
}
static __device__ __forceinline__ u32 cvtpk(float lo, float hi) {
    u32 r;
    asm("v_cvt_pk_bf16_f32 %0, %1, %2" : "=v"(r) : "v"(lo), "v"(hi));
    return r;
}
static __device__ __forceinline__ f32x4 mfma16(short8 a, short8 b, f32x4 c) {
    return __builtin_amdgcn_mfma_f32_16x16x32_bf16(a, b, c, 0, 0, 0);
}
static __device__ __forceinline__ void gload_lds16(const void* g, void* l) {
    __builtin_amdgcn_global_load_lds(
        (const __attribute__((address_space(1))) void*)g,
        (__attribute__((address_space(3))) void*)l, 16, 0, 0);
}

// ---------------- cast x (fp32 -> bf16), vectorized ----------------
__global__ void cast_x_kernel(const float* __restrict__ x, u16* __restrict__ xb, int n) {
    int i = (blockIdx.x * blockDim.x + threadIdx.x) * 4;
    int stride = gridDim.x * blockDim.x * 4;
    for (; i < n; i += stride) {
        f32x4 v = *(const f32x4*)&x[i];
        u16x4 o;
        o.x = f2bf(v.x); o.y = f2bf(v.y); o.z = f2bf(v.z); o.w = f2bf(v.w);
        *(u16x4*)&xb[i] = o;
    }
}

// ---------------- transpose + cast: src[R][C] fp32 -> dst[C][R] bf16 ----------------
__global__ void transpose_cast_kernel(const float* __restrict__ src, u16* __restrict__ dst,
                                      int R, int C) {
    __shared__ float tile[32][33];
    int c0 = blockIdx.x * 32, r0 = blockIdx.y * 32;
    int tx = threadIdx.x, ty = threadIdx.y;
    tile[ty][tx] = src[(size_t)(r0 + ty) * C + c0 + tx];
    __syncthreads();
    dst[(size_t)(c0 + ty) * R + r0 + tx] = f2bf(tile[tx][ty]);
}

// ---------------- bf16 transpose: src[R][C] -> dst[C][R] ----------------
__global__ void transpose_bf16_kernel(const u16* __restrict__ src, u16* __restrict__ dst,
                                      int R, int C) {
    __shared__ u16 tile[32][33];
    int c0 = blockIdx.x * 32, r0 = blockIdx.y * 32;
    int tx = threadIdx.x, ty = threadIdx.y;
    tile[ty][tx] = src[(size_t)(r0 + ty) * C + c0 + tx];
    __syncthreads();
    dst[(size_t)(c0 + ty) * R + r0 + tx] = tile[tx][ty];
}

// ---------------- fused LoRA weight fold + transpose + cast ----------------
// dst[C][R] bf16 = (W[R][C] + 2 * A[R][16] @ Bm[16][C])^T
__global__ void fused_wT_kernel(const float* __restrict__ W, const float* __restrict__ A,
                                const float* __restrict__ Bm, u16* __restrict__ dst,
                                int R, int C) {
    __shared__ float tile[32][33];
    __shared__ float As[32][17];
    __shared__ float Bs[16][33];
    int c0 = blockIdx.x * 32, r0 = blockIdx.y * 32;
    int tx = threadIdx.x, ty = threadIdx.y;
    tile[ty][tx] = W[(size_t)(r0 + ty) * C + c0 + tx];
    if (tx < 16) As[ty][tx] = A[(r0 + ty) * 16 + tx];
    if (ty < 16) Bs[ty][tx] = Bm[(size_t)ty * C + c0 + tx];
    __syncthreads();
    float acc = 0.0f;
#pragma unroll
    for (int rr = 0; rr < 16; ++rr) acc += As[tx][rr] * Bs[rr][ty];
    dst[(size_t)(c0 + ty) * R + r0 + tx] = f2bf(tile[tx][ty] + 2.0f * acc);
}

// ---------------- GEMM: 128x128 tile, BK=64, dbuf DMA + counted vmcnt + T2 swizzle ----
// C[M][*] = A[M][2048] @ Bt[Nn][2048]^T
// LDS: linear dest (global_load_lds), SOURCE slice pre-swizzled by (lane&7)^l8,
// fragment reads XOR the slice with (row&7) — same involution (rule #21).
// MODE 1: f32 out (stride Nn). MODE 2: QKV split (q 2048 / k 512 / v 512).
template <int MODE, int CN>
__global__ __launch_bounds__(256) void gemm_kernel(
    const u16* __restrict__ A, const u16* __restrict__ Bt, void* __restrict__ C0,
    void* __restrict__ C1, void* __restrict__ C2, int Nn) {
    constexpr int K = 2048;
    constexpr int NT = K / 64;
    __shared__ u16 As[2][128 * 64];
    __shared__ u16 Bs[2][128 * 64];
    const int tid = threadIdx.x;
    const int wid = tid >> 6, lane = tid & 63;
    // 2D-chunked XCD swizzle
    const int flat = blockIdx.y * gridDim.x + blockIdx.x;
    const int xcd = flat & 7, local = flat >> 3;
    const int mbase = (((xcd & 3) << 3) + (local & 7)) * 128;
    const int nbase = ((xcd >> 2) * CN + (local >> 3)) * 128;
    const int wrow = (wid >> 1) * 64, wcol = (wid & 1) * 64;
    const int fr = lane & 15, hi = lane >> 4, fk = hi * 8;
    const int l8 = lane >> 3;
    const int swc = ((lane & 7) ^ l8) * 8;     // pre-swizzled source 16B-slice
    const int rs = fr & 7;                     // read-side XOR key (= row & 7)
    f32x4 acc[4][4] = {};
    const u16* Ag = A + (size_t)mbase * K;
    const u16* Bg = Bt + (size_t)nbase * K;

    auto STAGE = [&](int kt, int buf) {
#pragma unroll
        for (int i = 0; i < 4; ++i) {
            const int r8 = (i * 4 + wid) * 8;
            gload_lds16(&Ag[(size_t)(r8 + l8) * K + kt * 64 + swc], &As[buf][r8 * 64]);
            gload_lds16(&Bg[(size_t)(r8 + l8) * K + kt * 64 + swc], &Bs[buf][r8 * 64]);
        }
    };

    STAGE(0, 0);
    for (int kt = 0; kt < NT; ++kt) {
        const int cur = kt & 1;
        if (kt < NT - 1) {
            STAGE(kt + 1, cur ^ 1);                            // prefetch stays in flight
            asm volatile("s_waitcnt vmcnt(8)" ::: "memory");   // wait only current tile
        } else {
            asm volatile("s_waitcnt vmcnt(0)" ::: "memory");
        }
        __builtin_amdgcn_s_barrier();                          // buf[cur] published
#pragma unroll
        for (int ks = 0; ks < 2; ++ks) {
            short8 af[4], bfr[4];
#pragma unroll
            for (int i = 0; i < 4; ++i) {
                const int arow = wrow + i * 16 + fr;
                const int brow = wcol + i * 16 + fr;
                af[i]  = *(const short8*)&As[cur][arow * 64 + (((ks * 4 + hi) ^ rs) * 8)];
                bfr[i] = *(const short8*)&Bs[cur][brow * 64 + (((ks * 4 + hi) ^ rs) * 8)];
            }
#pragma unroll
            for (int mi = 0; mi < 4; ++mi)
#pragma unroll
                for (int ni = 0; ni < 4; ++ni)
                    acc[mi][ni] = mfma16(af[mi], bfr[ni], acc[mi][ni]);
        }
        __builtin_amdgcn_s_barrier();                          // reads done before overwrite
    }
    const int rb = mbase + wrow + (hi << 2);
    const int cb = nbase + wcol + fr;
    if (MODE == 1) {
        float* C = (float*)C0;
#pragma unroll
        for (int mi = 0; mi < 4; ++mi)
#pragma unroll
            for (int j = 0; j < 4; ++j) {
                const size_t ro = (size_t)(rb + mi * 16 + j) * Nn;
#pragma unroll
                for (int ni = 0; ni < 4; ++ni) C[ro + cb + ni * 16] = acc[mi][ni][j];
            }
    } else {
        u16* C;
        int cstride, cc;
        if (nbase < 2048)      { C = (u16*)C0; cstride = 2048; cc = cb; }
        else if (nbase < 2560) { C = (u16*)C1; cstride = 512;  cc = cb - 2048; }
        else                   { C = (u16*)C2; cstride = 512;  cc = cb - 2560; }
#pragma unroll
        for (int mi = 0; mi < 4; ++mi)
#pragma unroll
            for (int j = 0; j < 4; ++j) {
                const size_t ro = (size_t)(rb + mi * 16 + j) * cstride;
#pragma unroll
                for (int ni = 0; ni < 4; ++ni) C[ro + cc + ni * 16] = f2bf(acc[mi][ni][j]);
            }
    }
}

// ---------------- RoPE in place on bf16 [4096][width], optional pre-scale ----------------
__global__ void rope_kernel(u16* __restrict__ t, const float* __restrict__ cosb,
                            const float* __restrict__ sinb, int width, int shift, float scale) {
    int idx = blockIdx.x * blockDim.x + threadIdx.x;
    int base = idx * 8;
    int row = base >> shift;
    int within = base & (width - 1);
    int d0 = within & 63;
    int i0 = d0 >> 1;
    int s = row & 1023;
    short8 v = *(short8*)&t[base];
    f32x4 cv = *(const f32x4*)&cosb[s * 32 + i0];
    f32x4 sv = *(const f32x4*)&sinb[s * 32 + i0];
#pragma unroll
    for (int p = 0; p < 4; ++p) {
        float c = cv[p] * scale, sn = sv[p] * scale;
        float x0 = bf2f((u16)v[2 * p]);
        float x1 = bf2f((u16)v[2 * p + 1]);
        float r0 = x0 * c - x1 * sn;
        float r1 = x0 * sn + x1 * c;
        v[2 * p] = (short)f2bf(r0);
        v[2 * p + 1] = (short)f2bf(r1);
    }
    *(short8*)&t[base] = v;
}

// ---------------- attention tile step ----------------
template <bool DIAG>
static __device__ __forceinline__ void attn_tile_step(
    const u16* __restrict__ Ksb, const u16* __restrict__ Vsb,
    const short8* qf, f32x4* o, float& m, float& l,
    int sq, int kvb, int wid, int fr, int hi) {
    f32x4 s[4];
    const int sw = fr & 7;
#pragma unroll
    for (int mi = 0; mi < 4; ++mi) {
        if (!DIAG || mi <= wid) {
            const int row = (mi * 16 + fr) * 64;
            short8 kf0 = *(const short8*)&Ksb[row + ((hi ^ sw) * 8)];
            short8 kf1 = *(const short8*)&Ksb[row + (((4 + hi) ^ sw) * 8)];
            f32x4 z = {};
            z = mfma16(kf0, qf[0], z);
            z = mfma16(kf1, qf[1], z);
#pragma unroll
            for (int j = 0; j < 4; ++j) {
                float val = z[j];
                if (DIAG && mi == wid && (kvb + mi * 16 + hi * 4 + j > sq)) val = -3.0e38f;
                s[mi][j] = val;
            }
        } else {
            s[mi][0] = -3.0e38f; s[mi][1] = -3.0e38f;
            s[mi][2] = -3.0e38f; s[mi][3] = -3.0e38f;
        }
    }
    float pmax = fmaxf(fmaxf(fmaxf(s[0][0], s[0][1]), fmaxf(s[0][2], s[0][3])),
                       fmaxf(fmaxf(s[1][0], s[1][1]), fmaxf(s[1][2], s[1][3])));
    pmax = fmaxf(pmax, fmaxf(fmaxf(fmaxf(s[2][0], s[2][1]), fmaxf(s[2][2], s[2][3])),
                             fmaxf(fmaxf(s[3][0], s[3][1]), fmaxf(s[3][2], s[3][3]))));
    pmax = fmaxf(pmax, __shfl_xor(pmax, 16));
    pmax = fmaxf(pmax, __shfl_xor(pmax, 32));
    if (__any(pmax > m + 8.0f)) {
        const float mnew = fmaxf(m, pmax);
        const float fsc = exp2f(m - mnew);
        l *= fsc;
        m = mnew;
#pragma unroll
        for (int dn = 0; dn < 4; ++dn)
#pragma unroll
            for (int j = 0; j < 4; ++j) o[dn][j] *= fsc;
    }
    float rs = 0.0f;
    u32 pk[4][2];
#pragma unroll
    for (int mi = 0; mi < 4; ++mi) {
        float p0 = exp2f(s[mi][0] - m);
        float p1 = exp2f(s[mi][1] - m);
        float p2 = exp2f(s[mi][2] - m);
        float p3 = exp2f(s[mi][3] - m);
        rs += (p0 + p1) + (p2 + p3);
        pk[mi][0] = cvtpk(p0, p1);
        pk[mi][1] = cvtpk(p2, p3);
    }
    rs += __shfl_xor(rs, 16);
    rs += __shfl_xor(rs, 32);
    l += rs;
    const int ksmax = DIAG ? (wid >> 1) : 1;
#pragma unroll
    for (int ks = 0; ks < 2; ++ks) {
        if (ks > ksmax) continue;
        u32 w0 = pk[2 * ks][0], w2 = pk[2 * ks + 1][0];
        u32 w1 = pk[2 * ks][1], w3 = pk[2 * ks + 1][1];
        asm volatile("v_permlane32_swap_b32 %0, %1" : "+v"(w0), "+v"(w2));
        asm volatile("v_permlane16_swap_b32 %0, %1" : "+v"(w0), "+v"(w2));
        asm volatile("v_permlane32_swap_b32 %0, %1" : "+v"(w1), "+v"(w3));
        asm volatile("v_permlane16_swap_b32 %0, %1" : "+v"(w1), "+v"(w3));
        union { u32 w[4]; short8 s8; } pu;
        pu.w[0] = w0; pu.w[1] = w1; pu.w[2] = w2; pu.w[3] = w3;
        short8 pf = pu.s8;
#pragma unroll
        for (int dn = 0; dn < 4; ++dn) {
            const int row = (dn * 16 + fr) * 64;
            short8 vf = *(const short8*)&Vsb[row + (((ks * 4 + hi) ^ sw) * 8)];
            o[dn] = mfma16(vf, pf, o[dn]);
        }
    }
}

// ---------------- causal GQA flash attention, paired q-tiles, DMA-staged K/V ----------
__global__ __launch_bounds__(256) void attn_kernel(
    const u16* __restrict__ q, const u16* __restrict__ k, const u16* __restrict__ vt,
    u16* __restrict__ ctx) {
    __shared__ u16 Ks[2][64 * 64];
    __shared__ u16 Vs[2][64 * 64];
    const int jp = blockIdx.x, h = blockIdx.y, b = blockIdx.z;
    const int qtA = jp, qtB = 15 - jp;
    const int g = h >> 2;
    const int tid = threadIdx.x, wid = tid >> 6, lane = tid & 63;
    const int fr = lane & 15, hi = lane >> 4, fk = hi * 8;
    const int sqA = qtA * 64 + wid * 16 + fr;
    const int sqB = qtB * 64 + wid * 16 + fr;
    short8 qfA[2], qfB[2];
    {
        const u16* qp = &q[((size_t)(b * 1024 + sqA)) * 2048 + h * 64];
        qfA[0] = *(const short8*)&qp[fk];
        qfA[1] = *(const short8*)&qp[32 + fk];
        const u16* qp2 = &q[((size_t)(b * 1024 + sqB)) * 2048 + h * 64];
        qfB[0] = *(const short8*)&qp2[fk];
        qfB[1] = *(const short8*)&qp2[32 + fk];
    }
    f32x4 oA[4] = {}, oB[4] = {};
    float mA = -3.0e38f, lA = 0.0f, mB = -3.0e38f, lB = 0.0f;
    const u16* kbase = k + ((size_t)b * 1024) * 512 + g * 64;
    const u16* vbase = vt + ((size_t)(g * 64)) * 4096 + b * 1024;
    const int l8 = lane >> 3;
    const int sw8 = ((lane & 7) ^ l8) * 8;

    auto stage = [&](int kt, int buf) {
        const u16* kg = kbase + (size_t)(kt * 64) * 512;
        const u16* vg = vbase + kt * 64;
#pragma unroll
        for (int i = 0; i < 2; ++i) {
            const int r8 = (i * 4 + wid) * 8;
            gload_lds16(&kg[(size_t)(r8 + l8) * 512 + sw8], &Ks[buf][r8 * 64]);
            gload_lds16(&vg[(size_t)(r8 + l8) * 4096 + sw8], &Vs[buf][r8 * 64]);
        }
    };

    stage(0, 0);
    for (int kt = 0; kt <= qtB; ++kt) {
        const int cur = kt & 1;
        __syncthreads();                       // publishes buf[cur]
        if (kt < qtB) stage(kt + 1, cur ^ 1);  // async prefetch under compute
        const int kvb = kt * 64;
        if (kt < qtA)
            attn_tile_step<false>(Ks[cur], Vs[cur], qfA, oA, mA, lA, sqA, kvb, wid, fr, hi);
        else if (kt == qtA)
            attn_tile_step<true>(Ks[cur], Vs[cur], qfA, oA, mA, lA, sqA, kvb, wid, fr, hi);
        if (kt < qtB)
            attn_tile_step<false>(Ks[cur], Vs[cur], qfB, oB, mB, lB, sqB, kvb, wid, fr, hi);
        else
            attn_tile_step<true>(Ks[cur], Vs[cur], qfB, oB, mB, lB, sqB, kvb, wid, fr, hi);
    }
    {
        const float linv = 1.0f / lA;
        const size_t obase = ((size_t)(b * 1024 + sqA)) * 2048 + h * 64;
#pragma unroll
        for (int dn = 0; dn < 4; ++dn) {
            u16x4 w;
#pragma unroll
            for (int j = 0; j < 4; ++j) w[j] = f2bf(oA[dn][j] * linv);
            *(u16x4*)&ctx[obase + dn * 16 + hi * 4] = w;
        }
    }
    {
        const float linv = 1.0f / lB;
        const size_t obase = ((size_t)(b * 1024 + sqB)) * 2048 + h * 64;
#pragma unroll
        for (int dn = 0; dn < 4; ++dn) {
            u16x4 w;
#pragma unroll
            for (int j = 0; j < 4; ++j) w[j] = f2bf(oB[dn][j] * linv);
            *(u16x4*)&ctx[obase + dn * 16 + hi * 4] = w;
        }
    }
}

extern "C" void kernel_launch(void* const* d_in, const int* in_sizes, int n_in,
                              void* d_out, int out_size, void* d_ws, size_t ws_size,
                              hipStream_t stream) {
    const float* x    = (const float*)d_in[0];
    const float* fcos = (const float*)d_in[1];
    const float* fsin = (const float*)d_in[2];
    const float* Wq   = (const float*)d_in[3];
    const float* Wk   = (const float*)d_in[4];
    const float* Wv   = (const float*)d_in[5];
    const float* Wo   = (const float*)d_in[6];
    const float* qA   = (const float*)d_in[7];
    const float* qB   = (const float*)d_in[8];
    const float* kA   = (const float*)d_in[9];
    const float* kB   = (const float*)d_in[10];
    const float* vA   = (const float*)d_in[11];
    const float* vB   = (const float*)d_in[12];
    float* out = (float*)d_out;

    char* ws = (char*)d_ws;
    size_t off = 0;
    auto alloc = [&](size_t bytes) { char* p = ws + off; off += (bytes + 255) & ~(size_t)255; return p; };
    u16* xb     = (u16*)alloc((size_t)4096 * 2048 * 2);
    u16* WqkvT  = (u16*)alloc((size_t)3072 * 2048 * 2);  // rows: 0..2047 q, 2048..2559 k, 2560..3071 v
    u16* WoT    = (u16*)alloc((size_t)2048 * 2048 * 2);
    u16* qbuf   = (u16*)alloc((size_t)4096 * 2048 * 2);
    u16* kbuf   = (u16*)alloc((size_t)4096 * 512 * 2);
    u16* vbuf   = (u16*)alloc((size_t)4096 * 512 * 2);
    u16* VT2    = (u16*)alloc((size_t)512 * 4096 * 2);   // V^T: [(g*64+d)][b*1024+s]
    u16* ctx    = (u16*)alloc((size_t)4096 * 2048 * 2);

    cast_x_kernel<<<2048, 256, 0, stream>>>(x, xb, 4096 * 2048);

    dim3 tb(32, 32);
    fused_wT_kernel<<<dim3(64, 64), tb, 0, stream>>>(Wq, qA, qB, WqkvT, 2048, 2048);
    fused_wT_kernel<<<dim3(16, 64), tb, 0, stream>>>(Wk, kA, kB, WqkvT + (size_t)2048 * 2048, 2048, 512);
    fused_wT_kernel<<<dim3(16, 64), tb, 0, stream>>>(Wv, vA, vB, WqkvT + (size_t)2560 * 2048, 2048, 512);
    transpose_cast_kernel<<<dim3(64, 64), tb, 0, stream>>>(Wo, WoT, 2048, 2048);

    // merged QKV projection: N = 3072, grid 32x24 = 768 blocks
    gemm_kernel<2, 12><<<dim3(32, 24), 256, 0, stream>>>(xb, WqkvT, qbuf, kbuf, vbuf, 3072);
    // V^T for attention
    transpose_bf16_kernel<<<dim3(16, 128), tb, 0, stream>>>(vbuf, VT2, 4096, 512);

    rope_kernel<<<4096, 256, 0, stream>>>(qbuf, fcos, fsin, 2048, 11, SCL2);  // q pre-scaled
    rope_kernel<<<1024, 256, 0, stream>>>(kbuf, fcos, fsin, 512, 9, 1.0f);

    attn_kernel<<<dim3(8, 32, 4), 256, 0, stream>>>(qbuf, kbuf, VT2, ctx);

    gemm_kernel<1, 8><<<dim3(32, 16), 256, 0, stream>>>(ctx, WoT, out, nullptr, nullptr, 2048);
}